// Round 4
// baseline (13005.859 us; speedup 1.0000x reference)
//
#include <hip/hip_runtime.h>
#include <cstdint>
#include <cstddef>

// ---------------------------------------------------------------------------
// CTC-CRF BLSTM pipeline for MI355X.  B=64 T=1024 IDIM=120 HDIM=320 K=72
// den == 0 analytically; batch sort is a no-op under the batch mean. Skipped.
//
// R12 deltas vs R11 (9.37 ms):
//  - Polling-primitive path abandoned (3 falsifications: sc0 load = stale L1;
//    XCD pairing = null; L2 atomic poll = engaged but not faster). The
//    exchange RT (~1.5-2Kcy) is irreducible from HIP; this round HIDES it.
//  - lstm_scan rewritten as a 2-stream interleave: 128 WGs, each owns two
//    batches (b, b+32) with the same (dir, half) -> same Whh registers.
//    Per step: dotA | gateA+pubA, pollB | dotB | gateB+pubB, pollA.
//    Each agent-scope poll targets a tag published ~one dot-phase earlier
//    by the lock-stepped partner WG, so the RT hides under compute.
//    Parity double-buffer + monotone tags; boundary polls skipped (state
//    crosses dispatches via hsave/csave). Agent-scope channel only.
// ---------------------------------------------------------------------------

typedef _Float16 f16;
typedef _Float16 h2v   __attribute__((ext_vector_type(2)));
typedef _Float16 f16x4v __attribute__((ext_vector_type(4)));
typedef _Float16 f16x8 __attribute__((ext_vector_type(8)));
typedef float    f32x4 __attribute__((ext_vector_type(4)));
typedef uint32_t u32x4 __attribute__((ext_vector_type(4)));

#define NEGF (-1e30f)
#define CT 128

__device__ __forceinline__ float dot2f(h2v a, h2v b, float c) {
#if __has_builtin(__builtin_amdgcn_fdot2)
  return __builtin_amdgcn_fdot2(a, b, c, false);
#else
  return c + (float)a.x * (float)b.x + (float)a.y * (float)b.y;
#endif
}

__device__ __forceinline__ float fast_rcp(float x) {
#if __has_builtin(__builtin_amdgcn_rcpf)
  return __builtin_amdgcn_rcpf(x);
#else
  return 1.f / x;
#endif
}
__device__ __forceinline__ float fsigm(float x) { return fast_rcp(1.f + __expf(-x)); }
__device__ __forceinline__ float ftanh(float x) { return 1.f - 2.f * fast_rcp(1.f + __expf(2.f * x)); }

__device__ __forceinline__ float fexp2(float x) {
#if __has_builtin(__builtin_amdgcn_exp2f)
  return __builtin_amdgcn_exp2f(x);
#else
  return exp2f(x);
#endif
}
__device__ __forceinline__ float flog2(float x) {
#if __has_builtin(__builtin_amdgcn_logf)
  return __builtin_amdgcn_logf(x);
#else
  return log2f(x);
#endif
}

__device__ __forceinline__ void stage16(f16* lds, const f16* g) {
#if __has_builtin(__builtin_amdgcn_global_load_lds)
  __builtin_amdgcn_global_load_lds(
      (const __attribute__((address_space(1))) uint32_t*)g,
      (__attribute__((address_space(3))) uint32_t*)lds, 16, 0, 0);
#else
  int lane = threadIdx.x & 63;
  *(f16x8*)&lds[lane * 8] = *(const f16x8*)g;
#endif
}

// ---------------------------- convert kernels ------------------------------

__global__ void conv_logits(const float* __restrict__ src, f16* __restrict__ dst) {
  int idx = blockIdx.x * 256 + threadIdx.x;      // < 65536*128
  int row = idx >> 7, k = idx & 127;
  dst[idx] = (f16)((k < 120) ? src[(size_t)row * 120 + k] : 0.f);
}

__global__ void conv_wt0(const float* __restrict__ w, f16* __restrict__ dst) {
  int idx = blockIdx.x * 256 + threadIdx.x;      // < 2560*128
  int n = idx >> 7, k = idx & 127;
  dst[idx] = (f16)((k < 120) ? w[(size_t)n * 120 + k] : 0.f);
}

__global__ void conv_copy(const float* __restrict__ src, f16* __restrict__ dst, int count) {
  int idx = blockIdx.x * 256 + threadIdx.x;
  if (idx < count) dst[idx] = (f16)src[idx];
}

__global__ void conv_wtl(const float* __restrict__ w, f16* __restrict__ dst) {
  int idx = blockIdx.x * 256 + threadIdx.x;      // < 128*640
  int n = idx / 640, k = idx % 640;
  dst[idx] = (f16)((n < 72) ? w[(size_t)n * 640 + k] : 0.f);
}

// Whh -> pair-packed scan layout (same as R6/R7).
__global__ void conv_whh(const float* __restrict__ whh0, const float* __restrict__ whh,
                         uint32_t* __restrict__ dst) {
  int o = blockIdx.x * 256 + threadIdx.x;        // < 6*2*200*512 = 1228800
  int tid = o & 511;
  int g  = o >> 9;
  int j  = g % 40;
  int g2 = g / 40;
  int i  = g2 % 5;
  int g3 = g2 / 5;                               // 0..11
  int hf = g3 & 1, slot = g3 >> 1;               // slot = layer*2+dir
  int tau = i * 512 + tid;
  int lr = tau >> 2, kq = tau & 3;
  int gate = lr / 160, u = lr - gate * 160;
  int r = gate * 320 + hf * 160 + u;
  int k = kq * 80 + j * 2;
  const float* srcm = (slot < 2) ? (whh0 + ((size_t)slot * 1280 + r) * 320)
                                 : (whh  + ((size_t)(slot - 2) * 1280 + r) * 320);
  f16 lo = (f16)srcm[k], hi = (f16)srcm[k + 1];
  dst[o] = (uint32_t)__builtin_bit_cast(unsigned short, lo) |
           ((uint32_t)__builtin_bit_cast(unsigned short, hi) << 16);
}

// --------------------- gather-GEMM for one time chunk ----------------------
__global__ __launch_bounds__(256)
void gemm_chunk(const f16* __restrict__ A, const f16* __restrict__ W,
                f16* __restrict__ gxc, const int* __restrict__ lens,
                int lda, int kTiles, int c0) {
  __shared__ __align__(16) f16 As[128 * 32];
  __shared__ __align__(16) f16 Ws[2][128 * 32];
  const int tid = threadIdx.x;
  const int lane = tid & 63, wid = tid >> 6;
  const int wm = wid >> 1, wn = wid & 1;
  const int dir = blockIdx.y >> 6, b = blockIdx.y & 63;
  const int n0 = blockIdx.x * 256;
  const int r_base = lane >> 2;                              // 0..15
  const int chs = ((((lane & 3) + (r_base >> 1)) & 3)) * 8;  // swizzled SRC k-chunk
  const int len = lens[b];

  f32x4 acc[4][8] = {};

  for (int kt = 0; kt < kTiles; ++kt) {
    const int k0 = kt * 32;
    __syncthreads();
#pragma unroll
    for (int hh = 0; hh < 2; ++hh) {
      const int c = wid * 2 + hh;
      const int j = c * 16 + r_base;                     // step within chunk
      const int s = c0 * CT + j;
      const int tt = dir ? ((s < len) ? (len - 1 - s) : s) : s;
      stage16(&As[c * 512], A + (size_t)(b * 1024 + tt) * lda + k0 + chs);
    }
#pragma unroll
    for (int hh = 0; hh < 4; ++hh) {
      const int c = wid * 4 + hh;                        // 0..15
      const int tile = c >> 3, cc = c & 7;
      stage16(&Ws[tile][cc * 512],
              W + (size_t)(dir * 1280 + n0 + tile * 128 + cc * 16 + r_base) * lda + k0 + chs);
    }
    __syncthreads();

    const int q = lane >> 4;                 // MFMA k-chunk
    const int l15 = lane & 15;
    const int cs = (q - (l15 >> 1)) & 3;     // swizzled slot holding chunk q
    const int rofs = l15 * 32 + cs * 8;      // f16 units within a 16-row chunk
    f16x8 av[4], wv0[4], wv1[4];
#pragma unroll
    for (int i = 0; i < 4; ++i)
      av[i] = *(const f16x8*)&As[(wm * 4 + i) * 512 + rofs];
#pragma unroll
    for (int i = 0; i < 4; ++i) {
      wv0[i] = *(const f16x8*)&Ws[0][(wn * 4 + i) * 512 + rofs];
      wv1[i] = *(const f16x8*)&Ws[1][(wn * 4 + i) * 512 + rofs];
    }
#pragma unroll
    for (int i = 0; i < 4; ++i)
#pragma unroll
      for (int j = 0; j < 4; ++j) {
        acc[i][j]     = __builtin_amdgcn_mfma_f32_16x16x32_f16(av[i], wv0[j], acc[i][j], 0, 0, 0);
        acc[i][4 + j] = __builtin_amdgcn_mfma_f32_16x16x32_f16(av[i], wv1[j], acc[i][4 + j], 0, 0, 0);
      }
  }

  const int r0 = (lane >> 4) * 4, cn = lane & 15;
  const size_t obase = (size_t)(dir * 64 + b) * CT;
#pragma unroll
  for (int i = 0; i < 4; ++i) {
    const int m = wm * 64 + i * 16 + r0;
#pragma unroll
    for (int j = 0; j < 4; ++j) {
      const int n = n0 + wn * 64 + j * 16 + cn;
#pragma unroll
      for (int r = 0; r < 4; ++r) {
        gxc[(obase + m + r) * 1280 + n]       = (f16)acc[i][j][r];
        gxc[(obase + m + r) * 1280 + n + 128] = (f16)acc[i][4 + j][r];
      }
    }
  }
}

// ------------------------- LSTM scan (one chunk) ---------------------------
// R12: 2-stream interleave. WG (pi, half) owns streams A=(bA,dir) and
// B=(bA+32,dir), sharing the same Whh_half registers. Per-step phases
// [dotA | gateA+pubA, pollB | dotB | gateB+pubB, pollA] hide the agent-scope
// exchange RT under the other stream's dot phase.
__global__ void __launch_bounds__(512)
__attribute__((amdgpu_waves_per_eu(2, 2)))
lstm_scan_chunk(const volatile uint32_t* wbuf,      // NOT restrict: may alias
                const f16* __restrict__ gxc,        // [2*64*CT][1280]
                const float* __restrict__ bias,     // [2][1280] this layer
                const int* __restrict__ lens,
                f16* xnext,                         // [65536][640] (no restrict)
                uint32_t* xq,                       // [512][160] tagged words
                f16* hsave,                         // [128][320]
                float* csave,                       // [256][160]
                int layer, int c0) {
  const int tid = threadIdx.x;
  const int wg = blockIdx.x;          // 0..127
  const int half = wg & 1;
  const int pi = wg >> 1;             // 0..63
  const int dir = pi & 1;
  const int bA = pi >> 1;             // 0..31
  const int bB = bA + 32;
  const int bdA = bA * 2 + dir, bdB = bB * 2 + dir;

  __shared__ __align__(16) f16 hbufA[320];
  __shared__ __align__(16) f16 hbufB[320];
  __shared__ float ylds[640];
  __shared__ __align__(16) f16 hstA[64 * 160];   // 20 KB ring, stream A
  __shared__ __align__(16) f16 hstB[64 * 160];   // 20 KB ring, stream B

  h2v w[5][40];
  {
    const volatile uint32_t* wb =
        wbuf + (size_t)((layer * 2 + dir) * 2 + half) * 200 * 512;
#pragma unroll
    for (int i = 0; i < 5; ++i)
#pragma unroll
      for (int j = 0; j < 40; ++j) {
        uint32_t v = wb[(i * 40 + j) * 512 + tid];
        w[i][j] = __builtin_bit_cast(h2v, v);
      }
  }
  if (tid < 320) {
    hbufA[tid] = (c0 == 0) ? (f16)0.f : hsave[bdA * 320 + tid];
    hbufB[tid] = (c0 == 0) ? (f16)0.f : hsave[bdB * 320 + tid];
  }

  const int lenA = lens[bA], lenB = lens[bB];
  const int kq = tid & 3;
  const int qi = tid >> 2;
  const int gu = half * 160 + tid;               // valid when tid<160
  float cA = 0.f, cB = 0.f;
  float bi = 0.f, bff = 0.f, bg = 0.f, bo = 0.f;
  if (tid < 160) {
    if (c0 > 0) {
      cA = csave[(half * 128 + bdA) * 160 + tid];
      cB = csave[(half * 128 + bdB) * 160 + tid];
    }
    const float* bp = bias + dir * 1280 + gu;
    bi = bp[0]; bff = bp[320]; bg = bp[640]; bo = bp[960];
  }
  __syncthreads();

  const size_t growA = (size_t)(dir * 64 + bA) * CT;
  const size_t growB = (size_t)(dir * 64 + bB) * CT;

  // full dot phase: y = Whh_half . h -> ylds (all 512 threads)
  auto dophase = [&](const f16* hb) {
    float a0 = 0.f, a1 = 0.f, a2 = 0.f, a3 = 0.f, a4 = 0.f;
    const u32x4* h4 = (const u32x4*)hb;
#pragma unroll
    for (int jb = 0; jb < 5; ++jb) {
      u32x4 p = h4[kq * 10 + jb * 2];
      u32x4 q = h4[kq * 10 + jb * 2 + 1];
      h2v hr[8];
#pragma unroll
      for (int j = 0; j < 4; ++j) hr[j] = __builtin_bit_cast(h2v, p[j]);
#pragma unroll
      for (int j = 0; j < 4; ++j) hr[4 + j] = __builtin_bit_cast(h2v, q[j]);
#pragma unroll
      for (int j = 0; j < 8; ++j) {
        a0 = dot2f(w[0][jb * 8 + j], hr[j], a0);
        a1 = dot2f(w[1][jb * 8 + j], hr[j], a1);
        a2 = dot2f(w[2][jb * 8 + j], hr[j], a2);
        a3 = dot2f(w[3][jb * 8 + j], hr[j], a3);
        a4 = dot2f(w[4][jb * 8 + j], hr[j], a4);
      }
    }
    float av[5] = {a0, a1, a2, a3, a4};
#pragma unroll
    for (int i = 0; i < 5; ++i) {
      float v = av[i];
      v += __shfl_xor(v, 1, 64);
      v += __shfl_xor(v, 2, 64);
      if (kq == 0) ylds[i * 128 + qi] = v;
    }
  };

  // flush 32 hstage rows [tw, tw+32) of one stream to xnext
  auto flush = [&](int tw, const f16* hst, int bX, int lenX) {
#pragma unroll
    for (int it = 0; it < 2; ++it) {
      const int slot = it * 512 + tid;
      if (slot < 640) {
        const int r = (int)(((unsigned)slot * 52429u) >> 20);  // slot/20
        const int j = slot - r * 20;
        const int sp = c0 * CT + tw + r;
        const int ttp = dir ? ((sp < lenX) ? (lenX - 1 - sp) : sp) : sp;
        f16x8 v = *(const f16x8*)&hst[((tw + r) & 63) * 160 + j * 8];
        *(f16x8*)&xnext[(size_t)(bX * 1024 + ttp) * 640 + dir * 320 + half * 160 + j * 8] = v;
      }
    }
  };

  for (int tl = 0; tl < CT; ++tl) {
    const int s = c0 * CT + tl;

    // gx loads for this step (both streams); HBM/L2 latency hides under dotA
    float gxiA = 0.f, gxfA = 0.f, gxgA = 0.f, gxoA = 0.f;
    float gxiB = 0.f, gxfB = 0.f, gxgB = 0.f, gxoB = 0.f;
    if (tid < 160) {
      const f16* gA = gxc + (growA + tl) * 1280 + gu;
      gxiA = (float)gA[0]; gxfA = (float)gA[320]; gxgA = (float)gA[640]; gxoA = (float)gA[960];
      const f16* gB = gxc + (growB + tl) * 1280 + gu;
      gxiB = (float)gB[0]; gxfB = (float)gB[320]; gxgB = (float)gB[640]; gxoB = (float)gB[960];
    }

    // ---- P1: dot A ----
    dophase(hbufA);
    if ((tl & 31) == 0 && tl > 0) {
      flush(tl - 32, hstA, bA, lenA);
      flush(tl - 32, hstB, bB, lenB);
    }
    __syncthreads();                              // B1: yldsA ready

    // ---- P2: gates A + publish A ; poll B (tag s) ----
    if (tid < 160) {
      const int u = tid;
      float pi_ = ylds[u]       + gxiA + bi;
      float pf_ = ylds[160 + u] + gxfA + bff;
      float pg_ = ylds[320 + u] + gxgA + bg;
      float po_ = ylds[480 + u] + gxoA + bo;
      float ig = fsigm(pi_), fg = fsigm(pf_), gg = ftanh(pg_), og = fsigm(po_);
      cA = fg * cA + ig * gg;
      float hv = og * ftanh(cA);
      const f16 hh = (f16)hv;
      const uint32_t tagA = (uint32_t)(layer * 1024 + s + 1);
      const uint32_t word = (tagA << 16) |
                            (uint32_t)__builtin_bit_cast(unsigned short, hh);
      __hip_atomic_store(&xq[((bdA * 2 + half) * 2 + (s & 1)) * 160 + u], word,
                         __ATOMIC_RELAXED, __HIP_MEMORY_SCOPE_AGENT);
      hbufA[gu] = hh;
      hstA[(tl & 63) * 160 + u] = hh;
    } else if (tid >= 256 && tid < 416 && tl > 0) {
      const int u = tid - 256;
      const uint32_t tagB = (uint32_t)(layer * 1024 + s);   // h_B(s)
      const int qidx = ((bdB * 2 + (1 - half)) * 2 + ((s - 1) & 1)) * 160 + u;
      uint32_t pw;
      int spins = 0;
      do {
        pw = __hip_atomic_load(&xq[qidx], __ATOMIC_RELAXED,
                               __HIP_MEMORY_SCOPE_AGENT);
      } while ((pw >> 16) != tagB && ++spins < 200000);
      hbufB[(1 - half) * 160 + u] =
          __builtin_bit_cast(f16, (unsigned short)(pw & 0xffffu));
    }
    __syncthreads();                              // B2: hbufB ready

    // ---- P3: dot B ----
    dophase(hbufB);
    __syncthreads();                              // B3: yldsB ready

    // ---- P4: gates B + publish B ; poll A (tag s+1) ----
    if (tid < 160) {
      const int u = tid;
      float pi_ = ylds[u]       + gxiB + bi;
      float pf_ = ylds[160 + u] + gxfB + bff;
      float pg_ = ylds[320 + u] + gxgB + bg;
      float po_ = ylds[480 + u] + gxoB + bo;
      float ig = fsigm(pi_), fg = fsigm(pf_), gg = ftanh(pg_), og = fsigm(po_);
      cB = fg * cB + ig * gg;
      float hv = og * ftanh(cB);
      const f16 hh = (f16)hv;
      const uint32_t tagB1 = (uint32_t)(layer * 1024 + s + 1);
      const uint32_t word = (tagB1 << 16) |
                            (uint32_t)__builtin_bit_cast(unsigned short, hh);
      __hip_atomic_store(&xq[((bdB * 2 + half) * 2 + (s & 1)) * 160 + u], word,
                         __ATOMIC_RELAXED, __HIP_MEMORY_SCOPE_AGENT);
      hbufB[gu] = hh;
      hstB[(tl & 63) * 160 + u] = hh;
    } else if (tid >= 256 && tid < 416 && tl + 1 < CT) {
      const int u = tid - 256;
      const uint32_t tagA1 = (uint32_t)(layer * 1024 + s + 1);  // h_A(s+1)
      const int qidx = ((bdA * 2 + (1 - half)) * 2 + (s & 1)) * 160 + u;
      uint32_t pw;
      int spins = 0;
      do {
        pw = __hip_atomic_load(&xq[qidx], __ATOMIC_RELAXED,
                               __HIP_MEMORY_SCOPE_AGENT);
      } while ((pw >> 16) != tagA1 && ++spins < 200000);
      hbufA[(1 - half) * 160 + u] =
          __builtin_bit_cast(f16, (unsigned short)(pw & 0xffffu));
    }
    __syncthreads();                              // B4: hbufA ready
  }

  flush(CT - 32, hstA, bA, lenA);
  flush(CT - 32, hstB, bB, lenB);
  if (tid < 160) {
    hsave[bdA * 320 + gu] = hbufA[gu];
    hsave[bdB * 320 + gu] = hbufB[gu];
    csave[(half * 128 + bdA) * 160 + tid] = cA;
    csave[(half * 128 + bdB) * 160 + tid] = cB;
  }
}

// ---------------------- projection GEMM (f32 out) --------------------------
__global__ __launch_bounds__(256)
void gemm_proj(const f16* __restrict__ A, const f16* __restrict__ W,
               float* __restrict__ outf, int lda, int kTiles, int ldo) {
  __shared__ __align__(16) f16 As[128 * 32];
  __shared__ __align__(16) f16 Ws[128 * 32];
  const int tid = threadIdx.x;
  const int lane = tid & 63, wid = tid >> 6;
  const int wm = wid >> 1, wn = wid & 1;
  const int m0 = blockIdx.y * 128, n0 = blockIdx.x * 128;
  const int r_base = lane >> 2;
  const int chs = ((((lane & 3) + (r_base >> 1)) & 3)) * 8;  // swizzled SRC chunk

  f32x4 acc[4][4] = {};

  for (int kt = 0; kt < kTiles; ++kt) {
    const int k0 = kt * 32;
    __syncthreads();
#pragma unroll
    for (int hh = 0; hh < 2; ++hh) {
      const int c = wid * 2 + hh;
      stage16(&As[c * 512], A + (size_t)(m0 + c * 16 + r_base) * lda + k0 + chs);
      stage16(&Ws[c * 512], W + (size_t)(n0 + c * 16 + r_base) * lda + k0 + chs);
    }
    __syncthreads();

    const int q = lane >> 4;
    const int l15 = lane & 15;
    const int cs = (q - (l15 >> 1)) & 3;
    const int rofs = l15 * 32 + cs * 8;
    f16x8 av[4], wv[4];
#pragma unroll
    for (int i = 0; i < 4; ++i)
      av[i] = *(const f16x8*)&As[(wm * 4 + i) * 512 + rofs];
#pragma unroll
    for (int i = 0; i < 4; ++i)
      wv[i] = *(const f16x8*)&Ws[(wn * 4 + i) * 512 + rofs];
#pragma unroll
    for (int i = 0; i < 4; ++i)
#pragma unroll
      for (int j = 0; j < 4; ++j)
        acc[i][j] = __builtin_amdgcn_mfma_f32_16x16x32_f16(av[i], wv[j], acc[i][j], 0, 0, 0);
  }

  const int r0 = (lane >> 4) * 4, cn = lane & 15;
#pragma unroll
  for (int i = 0; i < 4; ++i) {
    const int m = m0 + wm * 64 + i * 16 + r0;
#pragma unroll
    for (int j = 0; j < 4; ++j) {
      const int n = n0 + wn * 64 + j * 16 + cn;
#pragma unroll
      for (int r = 0; r < 4; ++r)
        outf[(size_t)(m + r) * ldo + n] = acc[i][j][r];
    }
  }
}

// ------------------------- logsumexp over K=72 ------------------------------
__global__ void lse_kernel(const float* __restrict__ Z, const float* __restrict__ b_lin,
                           float* __restrict__ lseout) {
  int row = blockIdx.x * 4 + (threadIdx.x >> 6);
  int l = threadIdx.x & 63;
  const float* z = Z + (size_t)row * 128;
  float v0 = (l < 72) ? z[l] + b_lin[l] : NEGF;
  float v1 = (l < 8) ? z[l + 64] + b_lin[l + 64] : NEGF;
  float m = fmaxf(v0, v1);
#pragma unroll
  for (int o = 32; o; o >>= 1) m = fmaxf(m, __shfl_xor(m, o, 64));
  float s = ((l < 72) ? __expf(v0 - m) : 0.f) + ((l < 8) ? __expf(v1 - m) : 0.f);
#pragma unroll
  for (int o = 32; o; o >>= 1) s += __shfl_xor(s, o, 64);
  if (l == 0) lseout[row] = m + __logf(s);
}

// --------------- emission pre-gather: emc[b][t][s] (f16) -------------------
// emc = (Z[t][ext[s]] + b_lin[ext[s]] - lse[t]) * log2(e).  Base-2 domain so
// the ctc recursion uses raw v_exp_f32 / v_log_f32.
__global__ void emz_kernel(const float* __restrict__ Z, const float* __restrict__ lse,
                           const float* __restrict__ b_lin,
                           const int* __restrict__ labels,
                           f16* __restrict__ emc) {
  const int b = blockIdx.y;
  const int t0 = blockIdx.x * 4;
  const int tid = threadIdx.x;   // 256
  __shared__ int ext[200];
  __shared__ float bls[200];
  if (tid < 200) {
    int e = (tid < 193 && (tid & 1)) ? labels[b * 96 + (tid >> 1)] : 0;
    ext[tid] = e;
    bls[tid] = b_lin[e];
  }
  __syncthreads();
#pragma unroll
  for (int dt = 0; dt < 4; ++dt) {
    const int t = t0 + dt;
    const float lst = lse[b * 1024 + t];
    const float* zr = Z + ((size_t)(b * 1024 + t)) * 128;
    for (int s = tid; s < 200; s += 256)
      emc[((size_t)(b * 1024 + t)) * 200 + s] =
          (f16)((zr[ext[s]] + bls[s] - lst) * 1.4426950408889634f);
  }
}

// ------------------------------ CTC forward ---------------------------------
__global__ void ctc_kernel(const f16* __restrict__ emc,
                           const int* __restrict__ labels, const int* __restrict__ inlen,
                           const int* __restrict__ lablen, float* __restrict__ num) {
  const int b = blockIdx.x;
  const int lane = threadIdx.x;          // 64
  __shared__ int ext[200];
  __shared__ float afin[200];

  for (int s = lane; s < 200; s += 64)
    ext[s] = (s < 193 && (s & 1)) ? labels[b * 96 + (s >> 1)] : 0;
  __syncthreads();

  const int L = lablen[b], len = inlen[b];
  const int Send = 2 * L + 1;
  const f16* eb = emc + (size_t)b * 1024 * 200;

  float a[4];
  bool  skp[4], val[4];
#pragma unroll
  for (int j = 0; j < 4; ++j) {
    const int s = lane * 4 + j;
    val[j] = (s < Send) && (s < 193);
    skp[j] = (s < 193) && (s & 1) && (s >= 2) && (ext[s] != ext[s - 2]);
  }
  {
    f16x4v e0 = *(const f16x4v*)&eb[lane * 4];   // t = 0
#pragma unroll
    for (int j = 0; j < 4; ++j) {
      const int s = lane * 4 + j;
      a[j] = (s <= 1 && val[j]) ? (float)e0[j] : NEGF;
    }
  }

  auto step = [&](f16x4v ev) {
    float p3 = __shfl_up(a[3], 1, 64);
    float p2 = __shfl_up(a[2], 1, 64);
    if (lane == 0) { p3 = NEGF; p2 = NEGF; }
    const float x2[4] = {p3, a[0], a[1], a[2]};
    const float x3[4] = {p2, p3, a[0], a[1]};
#pragma unroll
    for (int j = 0; j < 4; ++j) {
      const float xa = a[j], xb = x2[j];
      const float xc = skp[j] ? x3[j] : NEGF;
      const float m = fmaxf(xa, fmaxf(xb, xc));
      const float sum = fexp2(xa - m) + fexp2(xb - m) + fexp2(xc - m);
      const float nv = m + flog2(sum) + (float)ev[j];
      a[j] = val[j] ? nv : NEGF;
    }
  };

  // depth-8 register ring, fully static slot indexing
  f16x4v ring[8];
#pragma unroll
  for (int d = 1; d <= 8; ++d) {
    const int r = (d < len) ? d : (len - 1);
    ring[d & 7] = *(const f16x4v*)&eb[(size_t)r * 200 + lane * 4];
  }

  int t = 1;
  for (; t + 8 <= len; t += 8) {
#pragma unroll
    for (int k = 0; k < 8; ++k) {
      const int slot = (1 + k) & 7;        // t == 1 (mod 8)
      f16x4v ev = ring[slot];
      const int tp = t + k + 8;
      if (tp < len)
        ring[slot] = *(const f16x4v*)&eb[(size_t)tp * 200 + lane * 4];
      step(ev);
    }
  }
  for (; t < len; ++t)
    step(*(const f16x4v*)&eb[(size_t)t * 200 + lane * 4]);

#pragma unroll
  for (int j = 0; j < 4; ++j) {
    const int s = lane * 4 + j;
    if (s < 193) afin[s] = a[j];
  }
  __syncthreads();
  if (lane == 0) {
    const float aL = afin[2 * L], aLm1 = afin[2 * L - 1];
    const float m = fmaxf(aL, aLm1);
    // back to natural log for the final reduction
    num[b] = 0.6931471805599453f * (m + flog2(fexp2(aL - m) + fexp2(aLm1 - m)));
  }
}

__global__ void final_kernel(const float* __restrict__ num, float* __restrict__ out) {
  int l = threadIdx.x;  // 64
  float v = -1.1f * num[l];
#pragma unroll
  for (int o = 32; o; o >>= 1) v += __shfl_xor(v, o, 64);
  if (l == 0) out[0] = v * (1.f / 64.f);
}

__global__ void sentinel_kernel(float* __restrict__ out, float code) { out[0] = code; }

// ------------------------------ launcher ------------------------------------
extern "C" void kernel_launch(void* const* d_in, const int* in_sizes, int n_in,
                              void* d_out, int out_size, void* d_ws, size_t ws_size,
                              hipStream_t stream) {
  (void)in_sizes; (void)n_in; (void)out_size;

  const float* logits   = (const float*)d_in[0];
  const int*   labels   = (const int*)d_in[1];
  const int*   in_lens  = (const int*)d_in[2];
  const int*   lab_lens = (const int*)d_in[3];
  const float* Wih0     = (const float*)d_in[4];
  const float* Whh0     = (const float*)d_in[5];
  const float* b0       = (const float*)d_in[6];
  const float* Wih      = (const float*)d_in[7];
  const float* Whh      = (const float*)d_in[8];
  const float* bb       = (const float*)d_in[9];
  const float* W_lin    = (const float*)d_in[10];
  const float* b_lin    = (const float*)d_in[11];

  const size_t NEED = (size_t)224 * 1024 * 1024;
  if (ws_size < NEED) {
    sentinel_kernel<<<1, 1, 0, stream>>>((float*)d_out, -(float)(ws_size >> 20));
    return;
  }

  char* ws = (char*)d_ws;
  size_t off = 0;
  auto alloc = [&](size_t bytes) -> char* {
    char* p = ws + off;
    off += (bytes + 255) & ~(size_t)255;
    return p;
  };
  f16*      Xa     = (f16*)alloc((size_t)65536 * 640 * 2);        // 83.9 MB
  f16*      Xb     = (f16*)alloc((size_t)65536 * 640 * 2);        // 83.9 MB
  f16*      gxc    = (f16*)alloc((size_t)2 * 64 * CT * 1280 * 2); // 41.9 MB
  f16*      Wt0    = (f16*)alloc((size_t)2560 * 128 * 2);
  f16*      Wt12   = (f16*)alloc((size_t)2 * 2560 * 640 * 2);
  f16*      WtL    = (f16*)alloc((size_t)128 * 640 * 2);
  uint32_t* whh16  = (uint32_t*)alloc((size_t)6 * 2 * 200 * 512 * 4);
  float*    lseb   = (float*)alloc((size_t)65536 * 4);
  float*    num    = (float*)alloc(64 * 4);
  uint32_t* xq     = (uint32_t*)alloc((size_t)512 * 160 * 4);
  f16*      hsave  = (f16*)alloc((size_t)128 * 320 * 2);
  float*    csave  = (float*)alloc((size_t)256 * 160 * 4);
  // aliases (disjoint lifetimes)
  f16*      A0     = Xb;           // dead after layer 0; Xb first written layer 1
  float*    Z      = (float*)gxc;  // gxc dead after layer-2 scan
  f16*      emc    = Xa;           // Xa dead after gemm_proj

  hipMemsetAsync(xq, 0, (size_t)512 * 160 * 4, stream);

  conv_logits<<<32768, 256, 0, stream>>>(logits, A0);
  conv_wt0<<<1280, 256, 0, stream>>>(Wih0, Wt0);
  conv_copy<<<12800, 256, 0, stream>>>(Wih, Wt12, 3276800);
  conv_wtl<<<320, 256, 0, stream>>>(W_lin, WtL);
  conv_whh<<<4800, 256, 0, stream>>>(Whh0, Whh, whh16);

  // layer 0: A0 -> Xa
  for (int c = 0; c < 1024 / CT; ++c) {
    gemm_chunk<<<dim3(5, 128), 256, 0, stream>>>(A0, Wt0, gxc, in_lens, 128, 4, c);
    lstm_scan_chunk<<<128, 512, 0, stream>>>(whh16, gxc, b0, in_lens, Xa, xq,
                                             hsave, csave, 0, c);
  }
  // layer 1: Xa -> Xb
  for (int c = 0; c < 1024 / CT; ++c) {
    gemm_chunk<<<dim3(5, 128), 256, 0, stream>>>(Xa, Wt12, gxc, in_lens, 640, 20, c);
    lstm_scan_chunk<<<128, 512, 0, stream>>>(whh16, gxc, bb, in_lens, Xb, xq,
                                             hsave, csave, 1, c);
  }
  // layer 2: Xb -> Xa
  for (int c = 0; c < 1024 / CT; ++c) {
    gemm_chunk<<<dim3(5, 128), 256, 0, stream>>>(Xb, Wt12 + (size_t)2560 * 640, gxc,
                                                 in_lens, 640, 20, c);
    lstm_scan_chunk<<<128, 512, 0, stream>>>(whh16, gxc, bb + 2560, in_lens, Xa, xq,
                                             hsave, csave, 2, c);
  }
  // projection: Xa -> Z (f32)
  gemm_proj<<<dim3(1, 512), 256, 0, stream>>>(Xa, WtL, Z, 640, 20, 128);

  lse_kernel<<<16384, 256, 0, stream>>>(Z, b_lin, lseb);
  emz_kernel<<<dim3(256, 64), 256, 0, stream>>>(Z, lseb, b_lin, labels, emc);
  ctc_kernel<<<64, 64, 0, stream>>>(emc, labels, in_lens, lab_lens, num);
  final_kernel<<<1, 64, 0, stream>>>(num, (float*)d_out);
}

// Round 5
// 9390.900 us; speedup vs baseline: 1.3849x; 1.3849x over previous
//
#include <hip/hip_runtime.h>
#include <cstdint>
#include <cstddef>

// ---------------------------------------------------------------------------
// CTC-CRF BLSTM pipeline for MI355X.  B=64 T=1024 IDIM=120 HDIM=320 K=72
// den == 0 analytically; batch sort is a no-op under the batch mean. Skipped.
//
// R13 deltas vs R12 (13.0 ms, regression):
//  - Topology reverted to the proven R8 structure: 256 WGs (one per
//    (b,dir,half)), plain agent-scope exchange channel. R12 showed the
//    2-stream interleave hides ~1us of RT per stream but idles half the
//    CUs (128 WGs) -> net loss.
//  - NEW: 3-deep software-pipelined poll. The serial load-check loop
//    samples memory once per ~900cy (load RT). Keeping 3 loads in flight
//    (compiler emits minimal vmcnt(2) before each use) drops the sampling
//    period to ~RT/2, cutting the discovery term of the exchange exposure
//    by ~700-1200cy/step.
//  - All fast-channel / XCD-claim machinery deleted (R9-R11 falsified).
// ---------------------------------------------------------------------------

typedef _Float16 f16;
typedef _Float16 h2v   __attribute__((ext_vector_type(2)));
typedef _Float16 f16x4v __attribute__((ext_vector_type(4)));
typedef _Float16 f16x8 __attribute__((ext_vector_type(8)));
typedef float    f32x4 __attribute__((ext_vector_type(4)));
typedef uint32_t u32x4 __attribute__((ext_vector_type(4)));

#define NEGF (-1e30f)
#define CT 128

__device__ __forceinline__ float dot2f(h2v a, h2v b, float c) {
#if __has_builtin(__builtin_amdgcn_fdot2)
  return __builtin_amdgcn_fdot2(a, b, c, false);
#else
  return c + (float)a.x * (float)b.x + (float)a.y * (float)b.y;
#endif
}

__device__ __forceinline__ float fast_rcp(float x) {
#if __has_builtin(__builtin_amdgcn_rcpf)
  return __builtin_amdgcn_rcpf(x);
#else
  return 1.f / x;
#endif
}
__device__ __forceinline__ float fsigm(float x) { return fast_rcp(1.f + __expf(-x)); }
__device__ __forceinline__ float ftanh(float x) { return 1.f - 2.f * fast_rcp(1.f + __expf(2.f * x)); }

__device__ __forceinline__ float fexp2(float x) {
#if __has_builtin(__builtin_amdgcn_exp2f)
  return __builtin_amdgcn_exp2f(x);
#else
  return exp2f(x);
#endif
}
__device__ __forceinline__ float flog2(float x) {
#if __has_builtin(__builtin_amdgcn_logf)
  return __builtin_amdgcn_logf(x);
#else
  return log2f(x);
#endif
}

// 3-deep pipelined agent-scope poll: 3 loads kept in flight, each check
// waits only for the oldest (vmcnt(2)) -> sampling period ~RT/2 instead of
// RT. Tags are monotone, so any fresh sample is valid.
__device__ __forceinline__ uint32_t poll3(const uint32_t* p, uint32_t tag) {
  const volatile uint32_t* vp = (const volatile uint32_t*)p;
  uint32_t a = __hip_atomic_load(vp, __ATOMIC_RELAXED, __HIP_MEMORY_SCOPE_AGENT);
  uint32_t b = __hip_atomic_load(vp, __ATOMIC_RELAXED, __HIP_MEMORY_SCOPE_AGENT);
  uint32_t c = __hip_atomic_load(vp, __ATOMIC_RELAXED, __HIP_MEMORY_SCOPE_AGENT);
  int spins = 0;
  for (;;) {
    if ((a >> 16) == tag) return a;
    a = __hip_atomic_load(vp, __ATOMIC_RELAXED, __HIP_MEMORY_SCOPE_AGENT);
    if ((b >> 16) == tag) return b;
    b = __hip_atomic_load(vp, __ATOMIC_RELAXED, __HIP_MEMORY_SCOPE_AGENT);
    if ((c >> 16) == tag) return c;
    c = __hip_atomic_load(vp, __ATOMIC_RELAXED, __HIP_MEMORY_SCOPE_AGENT);
    if (++spins > 100000) return b;
  }
}

__device__ __forceinline__ void stage16(f16* lds, const f16* g) {
#if __has_builtin(__builtin_amdgcn_global_load_lds)
  __builtin_amdgcn_global_load_lds(
      (const __attribute__((address_space(1))) uint32_t*)g,
      (__attribute__((address_space(3))) uint32_t*)lds, 16, 0, 0);
#else
  int lane = threadIdx.x & 63;
  *(f16x8*)&lds[lane * 8] = *(const f16x8*)g;
#endif
}

// ---------------------------- convert kernels ------------------------------

__global__ void conv_logits(const float* __restrict__ src, f16* __restrict__ dst) {
  int idx = blockIdx.x * 256 + threadIdx.x;      // < 65536*128
  int row = idx >> 7, k = idx & 127;
  dst[idx] = (f16)((k < 120) ? src[(size_t)row * 120 + k] : 0.f);
}

__global__ void conv_wt0(const float* __restrict__ w, f16* __restrict__ dst) {
  int idx = blockIdx.x * 256 + threadIdx.x;      // < 2560*128
  int n = idx >> 7, k = idx & 127;
  dst[idx] = (f16)((k < 120) ? w[(size_t)n * 120 + k] : 0.f);
}

__global__ void conv_copy(const float* __restrict__ src, f16* __restrict__ dst, int count) {
  int idx = blockIdx.x * 256 + threadIdx.x;
  if (idx < count) dst[idx] = (f16)src[idx];
}

__global__ void conv_wtl(const float* __restrict__ w, f16* __restrict__ dst) {
  int idx = blockIdx.x * 256 + threadIdx.x;      // < 128*640
  int n = idx / 640, k = idx % 640;
  dst[idx] = (f16)((n < 72) ? w[(size_t)n * 640 + k] : 0.f);
}

// Whh -> pair-packed scan layout (same as R6/R7).
__global__ void conv_whh(const float* __restrict__ whh0, const float* __restrict__ whh,
                         uint32_t* __restrict__ dst) {
  int o = blockIdx.x * 256 + threadIdx.x;        // < 6*2*200*512 = 1228800
  int tid = o & 511;
  int g  = o >> 9;
  int j  = g % 40;
  int g2 = g / 40;
  int i  = g2 % 5;
  int g3 = g2 / 5;                               // 0..11
  int hf = g3 & 1, slot = g3 >> 1;               // slot = layer*2+dir
  int tau = i * 512 + tid;
  int lr = tau >> 2, kq = tau & 3;
  int gate = lr / 160, u = lr - gate * 160;
  int r = gate * 320 + hf * 160 + u;
  int k = kq * 80 + j * 2;
  const float* srcm = (slot < 2) ? (whh0 + ((size_t)slot * 1280 + r) * 320)
                                 : (whh  + ((size_t)(slot - 2) * 1280 + r) * 320);
  f16 lo = (f16)srcm[k], hi = (f16)srcm[k + 1];
  dst[o] = (uint32_t)__builtin_bit_cast(unsigned short, lo) |
           ((uint32_t)__builtin_bit_cast(unsigned short, hi) << 16);
}

// --------------------- gather-GEMM for one time chunk ----------------------
__global__ __launch_bounds__(256)
void gemm_chunk(const f16* __restrict__ A, const f16* __restrict__ W,
                f16* __restrict__ gxc, const int* __restrict__ lens,
                int lda, int kTiles, int c0) {
  __shared__ __align__(16) f16 As[128 * 32];
  __shared__ __align__(16) f16 Ws[2][128 * 32];
  const int tid = threadIdx.x;
  const int lane = tid & 63, wid = tid >> 6;
  const int wm = wid >> 1, wn = wid & 1;
  const int dir = blockIdx.y >> 6, b = blockIdx.y & 63;
  const int n0 = blockIdx.x * 256;
  const int r_base = lane >> 2;                              // 0..15
  const int chs = ((((lane & 3) + (r_base >> 1)) & 3)) * 8;  // swizzled SRC k-chunk
  const int len = lens[b];

  f32x4 acc[4][8] = {};

  for (int kt = 0; kt < kTiles; ++kt) {
    const int k0 = kt * 32;
    __syncthreads();
#pragma unroll
    for (int hh = 0; hh < 2; ++hh) {
      const int c = wid * 2 + hh;
      const int j = c * 16 + r_base;                     // step within chunk
      const int s = c0 * CT + j;
      const int tt = dir ? ((s < len) ? (len - 1 - s) : s) : s;
      stage16(&As[c * 512], A + (size_t)(b * 1024 + tt) * lda + k0 + chs);
    }
#pragma unroll
    for (int hh = 0; hh < 4; ++hh) {
      const int c = wid * 4 + hh;                        // 0..15
      const int tile = c >> 3, cc = c & 7;
      stage16(&Ws[tile][cc * 512],
              W + (size_t)(dir * 1280 + n0 + tile * 128 + cc * 16 + r_base) * lda + k0 + chs);
    }
    __syncthreads();

    const int q = lane >> 4;                 // MFMA k-chunk
    const int l15 = lane & 15;
    const int cs = (q - (l15 >> 1)) & 3;     // swizzled slot holding chunk q
    const int rofs = l15 * 32 + cs * 8;      // f16 units within a 16-row chunk
    f16x8 av[4], wv0[4], wv1[4];
#pragma unroll
    for (int i = 0; i < 4; ++i)
      av[i] = *(const f16x8*)&As[(wm * 4 + i) * 512 + rofs];
#pragma unroll
    for (int i = 0; i < 4; ++i) {
      wv0[i] = *(const f16x8*)&Ws[0][(wn * 4 + i) * 512 + rofs];
      wv1[i] = *(const f16x8*)&Ws[1][(wn * 4 + i) * 512 + rofs];
    }
#pragma unroll
    for (int i = 0; i < 4; ++i)
#pragma unroll
      for (int j = 0; j < 4; ++j) {
        acc[i][j]     = __builtin_amdgcn_mfma_f32_16x16x32_f16(av[i], wv0[j], acc[i][j], 0, 0, 0);
        acc[i][4 + j] = __builtin_amdgcn_mfma_f32_16x16x32_f16(av[i], wv1[j], acc[i][4 + j], 0, 0, 0);
      }
  }

  const int r0 = (lane >> 4) * 4, cn = lane & 15;
  const size_t obase = (size_t)(dir * 64 + b) * CT;
#pragma unroll
  for (int i = 0; i < 4; ++i) {
    const int m = wm * 64 + i * 16 + r0;
#pragma unroll
    for (int j = 0; j < 4; ++j) {
      const int n = n0 + wn * 64 + j * 16 + cn;
#pragma unroll
      for (int r = 0; r < 4; ++r) {
        gxc[(obase + m + r) * 1280 + n]       = (f16)acc[i][j][r];
        gxc[(obase + m + r) * 1280 + n + 128] = (f16)acc[i][4 + j][r];
      }
    }
  }
}

// ------------------------- LSTM scan (one chunk) ---------------------------
// R8 structure: 256 WGs, one (b,dir,half) stream each; agent-scope exchange.
// R13: consumer uses the 3-deep pipelined poll.
__global__ void __launch_bounds__(512)
__attribute__((amdgpu_waves_per_eu(2, 2)))
lstm_scan_chunk(const volatile uint32_t* wbuf,      // NOT restrict: may alias
                const f16* __restrict__ gxc,        // [2*64*CT][1280]
                const float* __restrict__ bias,     // [2][1280] this layer
                const int* __restrict__ lens,
                f16* xnext,                         // [65536][640] (no restrict)
                uint32_t* xq,                       // [512][160] tagged words
                f16* hsave,                         // [128][320]
                float* csave,                       // [256][160]
                int layer, int c0) {
  const int wg = blockIdx.x;
  const int half = wg >> 7;
  const int bd = wg & 127;
  const int b = bd >> 1, dir = bd & 1;
  const int tid = threadIdx.x;

  __shared__ __align__(16) f16 hbuf[320];
  __shared__ float ylds[640];
  __shared__ __align__(16) f16 hstage[64 * 160];   // 20 KB ring

  h2v w[5][40];
  {
    const volatile uint32_t* wb =
        wbuf + (size_t)((layer * 2 + dir) * 2 + half) * 200 * 512;
#pragma unroll
    for (int i = 0; i < 5; ++i)
#pragma unroll
      for (int j = 0; j < 40; ++j) {
        uint32_t v = wb[(i * 40 + j) * 512 + tid];
        w[i][j] = __builtin_bit_cast(h2v, v);
      }
  }
  if (tid < 320) hbuf[tid] = (c0 == 0) ? (f16)0.f : hsave[bd * 320 + tid];

  const int len = lens[b];
  const int kq = tid & 3;
  const int qi = tid >> 2;
  const int gu = half * 160 + tid;               // valid when tid<160
  float c_state = 0.f;
  float bi = 0.f, bff = 0.f, bg = 0.f, bo = 0.f;
  if (tid < 160) {
    if (c0 > 0) c_state = csave[wg * 160 + tid];
    const float* bp = bias + dir * 1280 + gu;
    bi = bp[0]; bff = bp[320]; bg = bp[640]; bo = bp[960];
  }
  __syncthreads();

  const size_t grow0 = (size_t)(dir * 64 + b) * CT;

  float gxi = 0.f, gxf = 0.f, gxg = 0.f, gxo = 0.f;
  if (tid < 160) {
    const f16* gp = gxc + grow0 * 1280 + gu;
    gxi = (float)gp[0]; gxf = (float)gp[320]; gxg = (float)gp[640]; gxo = (float)gp[960];
  }

  for (int tl = 0; tl < CT; ++tl) {
    const int s = c0 * CT + tl;
    const uint32_t tag = (uint32_t)(layer * 1024 + s + 1);

    float nxi = 0.f, nxf = 0.f, nxg = 0.f, nxo = 0.f;
    if (tid < 160 && tl + 1 < CT) {
      const f16* gp = gxc + (grow0 + tl + 1) * 1280 + gu;
      nxi = (float)gp[0]; nxf = (float)gp[320]; nxg = (float)gp[640]; nxo = (float)gp[960];
    }

    // ---- y = Whh_half . h  (all threads, b128 LDS reads; broadcast-free) ----
    float a0 = 0.f, a1 = 0.f, a2 = 0.f, a3 = 0.f, a4 = 0.f;
    {
      const u32x4* h4 = (const u32x4*)hbuf;
#pragma unroll
      for (int jb = 0; jb < 5; ++jb) {
        u32x4 p = h4[kq * 10 + jb * 2];
        u32x4 q = h4[kq * 10 + jb * 2 + 1];
        h2v hr[8];
#pragma unroll
        for (int j = 0; j < 4; ++j) hr[j] = __builtin_bit_cast(h2v, p[j]);
#pragma unroll
        for (int j = 0; j < 4; ++j) hr[4 + j] = __builtin_bit_cast(h2v, q[j]);
#pragma unroll
        for (int j = 0; j < 8; ++j) {
          a0 = dot2f(w[0][jb * 8 + j], hr[j], a0);
          a1 = dot2f(w[1][jb * 8 + j], hr[j], a1);
          a2 = dot2f(w[2][jb * 8 + j], hr[j], a2);
          a3 = dot2f(w[3][jb * 8 + j], hr[j], a3);
          a4 = dot2f(w[4][jb * 8 + j], hr[j], a4);
        }
      }
    }
    {
      float av[5] = {a0, a1, a2, a3, a4};
#pragma unroll
      for (int i = 0; i < 5; ++i) {
        float v = av[i];
        v += __shfl_xor(v, 1, 64);
        v += __shfl_xor(v, 2, 64);
        if (kq == 0) ylds[i * 128 + qi] = v;
      }
    }

    if ((tl & 31) == 0 && tl > 0) {
      const int tw = tl - 32;
#pragma unroll
      for (int it = 0; it < 2; ++it) {
        const int slot = it * 512 + tid;
        if (slot < 640) {
          const int r = (int)(((unsigned)slot * 52429u) >> 20);  // slot/20
          const int j = slot - r * 20;
          const int sp = c0 * CT + tw + r;
          const int ttp = dir ? ((sp < len) ? (len - 1 - sp) : sp) : sp;
          f16x8 v = *(const f16x8*)&hstage[((tw + r) & 63) * 160 + j * 8];
          *(f16x8*)&xnext[(size_t)(b * 1024 + ttp) * 640 + dir * 320 + half * 160 + j * 8] = v;
        }
      }
    }
    __syncthreads();                              // B1: ylds ready

    if (tid < 160) {
      const int u = tid;
      float pi = ylds[u]       + gxi + bi;
      float pf = ylds[160 + u] + gxf + bff;
      float pg = ylds[320 + u] + gxg + bg;
      float po = ylds[480 + u] + gxo + bo;
      float ig = fsigm(pi);
      float fg = fsigm(pf);
      float gg = ftanh(pg);
      float og = fsigm(po);
      c_state = fg * c_state + ig * gg;
      float hv = og * ftanh(c_state);
      const f16 hh = (f16)hv;
      const uint32_t word = (tag << 16) |
                            (uint32_t)__builtin_bit_cast(unsigned short, hh);
      __hip_atomic_store(&xq[((bd * 2 + half) * 2 + (s & 1)) * 160 + u], word,
                         __ATOMIC_RELAXED, __HIP_MEMORY_SCOPE_AGENT);
      hbuf[gu] = hh;
      hstage[(tl & 63) * 160 + u] = hh;
    } else if (tid >= 256 && tid < 416) {
      const int u = tid - 256;
      const uint32_t pw =
          poll3(&xq[((bd * 2 + (1 - half)) * 2 + (s & 1)) * 160 + u], tag);
      hbuf[(1 - half) * 160 + u] =
          __builtin_bit_cast(f16, (unsigned short)(pw & 0xffffu));
    }
    __syncthreads();                              // B2: hbuf ready for next dot

    gxi = nxi; gxf = nxf; gxg = nxg; gxo = nxo;
  }

  {
    const int tw = CT - 32;
#pragma unroll
    for (int it = 0; it < 2; ++it) {
      const int slot = it * 512 + tid;
      if (slot < 640) {
        const int r = (int)(((unsigned)slot * 52429u) >> 20);
        const int j = slot - r * 20;
        const int sp = c0 * CT + tw + r;
        const int ttp = dir ? ((sp < len) ? (len - 1 - sp) : sp) : sp;
        f16x8 v = *(const f16x8*)&hstage[((tw + r) & 63) * 160 + j * 8];
        *(f16x8*)&xnext[(size_t)(b * 1024 + ttp) * 640 + dir * 320 + half * 160 + j * 8] = v;
      }
    }
  }
  if (tid < 160) {
    hsave[bd * 320 + gu] = hbuf[gu];
    csave[wg * 160 + tid] = c_state;
  }
}

// ---------------------- projection GEMM (f32 out) --------------------------
__global__ __launch_bounds__(256)
void gemm_proj(const f16* __restrict__ A, const f16* __restrict__ W,
               float* __restrict__ outf, int lda, int kTiles, int ldo) {
  __shared__ __align__(16) f16 As[128 * 32];
  __shared__ __align__(16) f16 Ws[128 * 32];
  const int tid = threadIdx.x;
  const int lane = tid & 63, wid = tid >> 6;
  const int wm = wid >> 1, wn = wid & 1;
  const int m0 = blockIdx.y * 128, n0 = blockIdx.x * 128;
  const int r_base = lane >> 2;
  const int chs = ((((lane & 3) + (r_base >> 1)) & 3)) * 8;  // swizzled SRC chunk

  f32x4 acc[4][4] = {};

  for (int kt = 0; kt < kTiles; ++kt) {
    const int k0 = kt * 32;
    __syncthreads();
#pragma unroll
    for (int hh = 0; hh < 2; ++hh) {
      const int c = wid * 2 + hh;
      stage16(&As[c * 512], A + (size_t)(m0 + c * 16 + r_base) * lda + k0 + chs);
      stage16(&Ws[c * 512], W + (size_t)(n0 + c * 16 + r_base) * lda + k0 + chs);
    }
    __syncthreads();

    const int q = lane >> 4;
    const int l15 = lane & 15;
    const int cs = (q - (l15 >> 1)) & 3;
    const int rofs = l15 * 32 + cs * 8;
    f16x8 av[4], wv[4];
#pragma unroll
    for (int i = 0; i < 4; ++i)
      av[i] = *(const f16x8*)&As[(wm * 4 + i) * 512 + rofs];
#pragma unroll
    for (int i = 0; i < 4; ++i)
      wv[i] = *(const f16x8*)&Ws[(wn * 4 + i) * 512 + rofs];
#pragma unroll
    for (int i = 0; i < 4; ++i)
#pragma unroll
      for (int j = 0; j < 4; ++j)
        acc[i][j] = __builtin_amdgcn_mfma_f32_16x16x32_f16(av[i], wv[j], acc[i][j], 0, 0, 0);
  }

  const int r0 = (lane >> 4) * 4, cn = lane & 15;
#pragma unroll
  for (int i = 0; i < 4; ++i) {
    const int m = m0 + wm * 64 + i * 16 + r0;
#pragma unroll
    for (int j = 0; j < 4; ++j) {
      const int n = n0 + wn * 64 + j * 16 + cn;
#pragma unroll
      for (int r = 0; r < 4; ++r)
        outf[(size_t)(m + r) * ldo + n] = acc[i][j][r];
    }
  }
}

// ------------------------- logsumexp over K=72 ------------------------------
__global__ void lse_kernel(const float* __restrict__ Z, const float* __restrict__ b_lin,
                           float* __restrict__ lseout) {
  int row = blockIdx.x * 4 + (threadIdx.x >> 6);
  int l = threadIdx.x & 63;
  const float* z = Z + (size_t)row * 128;
  float v0 = (l < 72) ? z[l] + b_lin[l] : NEGF;
  float v1 = (l < 8) ? z[l + 64] + b_lin[l + 64] : NEGF;
  float m = fmaxf(v0, v1);
#pragma unroll
  for (int o = 32; o; o >>= 1) m = fmaxf(m, __shfl_xor(m, o, 64));
  float s = ((l < 72) ? __expf(v0 - m) : 0.f) + ((l < 8) ? __expf(v1 - m) : 0.f);
#pragma unroll
  for (int o = 32; o; o >>= 1) s += __shfl_xor(s, o, 64);
  if (l == 0) lseout[row] = m + __logf(s);
}

// --------------- emission pre-gather: emc[b][t][s] (f16) -------------------
// emc = (Z[t][ext[s]] + b_lin[ext[s]] - lse[t]) * log2(e).  Base-2 domain so
// the ctc recursion uses raw v_exp_f32 / v_log_f32.
__global__ void emz_kernel(const float* __restrict__ Z, const float* __restrict__ lse,
                           const float* __restrict__ b_lin,
                           const int* __restrict__ labels,
                           f16* __restrict__ emc) {
  const int b = blockIdx.y;
  const int t0 = blockIdx.x * 4;
  const int tid = threadIdx.x;   // 256
  __shared__ int ext[200];
  __shared__ float bls[200];
  if (tid < 200) {
    int e = (tid < 193 && (tid & 1)) ? labels[b * 96 + (tid >> 1)] : 0;
    ext[tid] = e;
    bls[tid] = b_lin[e];
  }
  __syncthreads();
#pragma unroll
  for (int dt = 0; dt < 4; ++dt) {
    const int t = t0 + dt;
    const float lst = lse[b * 1024 + t];
    const float* zr = Z + ((size_t)(b * 1024 + t)) * 128;
    for (int s = tid; s < 200; s += 256)
      emc[((size_t)(b * 1024 + t)) * 200 + s] =
          (f16)((zr[ext[s]] + bls[s] - lst) * 1.4426950408889634f);
  }
}

// ------------------------------ CTC forward ---------------------------------
__global__ void ctc_kernel(const f16* __restrict__ emc,
                           const int* __restrict__ labels, const int* __restrict__ inlen,
                           const int* __restrict__ lablen, float* __restrict__ num) {
  const int b = blockIdx.x;
  const int lane = threadIdx.x;          // 64
  __shared__ int ext[200];
  __shared__ float afin[200];

  for (int s = lane; s < 200; s += 64)
    ext[s] = (s < 193 && (s & 1)) ? labels[b * 96 + (s >> 1)] : 0;
  __syncthreads();

  const int L = lablen[b], len = inlen[b];
  const int Send = 2 * L + 1;
  const f16* eb = emc + (size_t)b * 1024 * 200;

  float a[4];
  bool  skp[4], val[4];
#pragma unroll
  for (int j = 0; j < 4; ++j) {
    const int s = lane * 4 + j;
    val[j] = (s < Send) && (s < 193);
    skp[j] = (s < 193) && (s & 1) && (s >= 2) && (ext[s] != ext[s - 2]);
  }
  {
    f16x4v e0 = *(const f16x4v*)&eb[lane * 4];   // t = 0
#pragma unroll
    for (int j = 0; j < 4; ++j) {
      const int s = lane * 4 + j;
      a[j] = (s <= 1 && val[j]) ? (float)e0[j] : NEGF;
    }
  }

  auto step = [&](f16x4v ev) {
    float p3 = __shfl_up(a[3], 1, 64);
    float p2 = __shfl_up(a[2], 1, 64);
    if (lane == 0) { p3 = NEGF; p2 = NEGF; }
    const float x2[4] = {p3, a[0], a[1], a[2]};
    const float x3[4] = {p2, p3, a[0], a[1]};
#pragma unroll
    for (int j = 0; j < 4; ++j) {
      const float xa = a[j], xb = x2[j];
      const float xc = skp[j] ? x3[j] : NEGF;
      const float m = fmaxf(xa, fmaxf(xb, xc));
      const float sum = fexp2(xa - m) + fexp2(xb - m) + fexp2(xc - m);
      const float nv = m + flog2(sum) + (float)ev[j];
      a[j] = val[j] ? nv : NEGF;
    }
  };

  // depth-8 register ring, fully static slot indexing
  f16x4v ring[8];
#pragma unroll
  for (int d = 1; d <= 8; ++d) {
    const int r = (d < len) ? d : (len - 1);
    ring[d & 7] = *(const f16x4v*)&eb[(size_t)r * 200 + lane * 4];
  }

  int t = 1;
  for (; t + 8 <= len; t += 8) {
#pragma unroll
    for (int k = 0; k < 8; ++k) {
      const int slot = (1 + k) & 7;        // t == 1 (mod 8)
      f16x4v ev = ring[slot];
      const int tp = t + k + 8;
      if (tp < len)
        ring[slot] = *(const f16x4v*)&eb[(size_t)tp * 200 + lane * 4];
      step(ev);
    }
  }
  for (; t < len; ++t)
    step(*(const f16x4v*)&eb[(size_t)t * 200 + lane * 4]);

#pragma unroll
  for (int j = 0; j < 4; ++j) {
    const int s = lane * 4 + j;
    if (s < 193) afin[s] = a[j];
  }
  __syncthreads();
  if (lane == 0) {
    const float aL = afin[2 * L], aLm1 = afin[2 * L - 1];
    const float m = fmaxf(aL, aLm1);
    // back to natural log for the final reduction
    num[b] = 0.6931471805599453f * (m + flog2(fexp2(aL - m) + fexp2(aLm1 - m)));
  }
}

__global__ void final_kernel(const float* __restrict__ num, float* __restrict__ out) {
  int l = threadIdx.x;  // 64
  float v = -1.1f * num[l];
#pragma unroll
  for (int o = 32; o; o >>= 1) v += __shfl_xor(v, o, 64);
  if (l == 0) out[0] = v * (1.f / 64.f);
}

__global__ void sentinel_kernel(float* __restrict__ out, float code) { out[0] = code; }

// ------------------------------ launcher ------------------------------------
extern "C" void kernel_launch(void* const* d_in, const int* in_sizes, int n_in,
                              void* d_out, int out_size, void* d_ws, size_t ws_size,
                              hipStream_t stream) {
  (void)in_sizes; (void)n_in; (void)out_size;

  const float* logits   = (const float*)d_in[0];
  const int*   labels   = (const int*)d_in[1];
  const int*   in_lens  = (const int*)d_in[2];
  const int*   lab_lens = (const int*)d_in[3];
  const float* Wih0     = (const float*)d_in[4];
  const float* Whh0     = (const float*)d_in[5];
  const float* b0       = (const float*)d_in[6];
  const float* Wih      = (const float*)d_in[7];
  const float* Whh      = (const float*)d_in[8];
  const float* bb       = (const float*)d_in[9];
  const float* W_lin    = (const float*)d_in[10];
  const float* b_lin    = (const float*)d_in[11];

  const size_t NEED = (size_t)224 * 1024 * 1024;
  if (ws_size < NEED) {
    sentinel_kernel<<<1, 1, 0, stream>>>((float*)d_out, -(float)(ws_size >> 20));
    return;
  }

  char* ws = (char*)d_ws;
  size_t off = 0;
  auto alloc = [&](size_t bytes) -> char* {
    char* p = ws + off;
    off += (bytes + 255) & ~(size_t)255;
    return p;
  };
  f16*      Xa     = (f16*)alloc((size_t)65536 * 640 * 2);        // 83.9 MB
  f16*      Xb     = (f16*)alloc((size_t)65536 * 640 * 2);        // 83.9 MB
  f16*      gxc    = (f16*)alloc((size_t)2 * 64 * CT * 1280 * 2); // 41.9 MB
  f16*      Wt0    = (f16*)alloc((size_t)2560 * 128 * 2);
  f16*      Wt12   = (f16*)alloc((size_t)2 * 2560 * 640 * 2);
  f16*      WtL    = (f16*)alloc((size_t)128 * 640 * 2);
  uint32_t* whh16  = (uint32_t*)alloc((size_t)6 * 2 * 200 * 512 * 4);
  float*    lseb   = (float*)alloc((size_t)65536 * 4);
  float*    num    = (float*)alloc(64 * 4);
  uint32_t* xq     = (uint32_t*)alloc((size_t)512 * 160 * 4);
  f16*      hsave  = (f16*)alloc((size_t)128 * 320 * 2);
  float*    csave  = (float*)alloc((size_t)256 * 160 * 4);
  // aliases (disjoint lifetimes)
  f16*      A0     = Xb;           // dead after layer 0; Xb first written layer 1
  float*    Z      = (float*)gxc;  // gxc dead after layer-2 scan
  f16*      emc    = Xa;           // Xa dead after gemm_proj

  hipMemsetAsync(xq, 0, (size_t)512 * 160 * 4, stream);

  conv_logits<<<32768, 256, 0, stream>>>(logits, A0);
  conv_wt0<<<1280, 256, 0, stream>>>(Wih0, Wt0);
  conv_copy<<<12800, 256, 0, stream>>>(Wih, Wt12, 3276800);
  conv_wtl<<<320, 256, 0, stream>>>(W_lin, WtL);
  conv_whh<<<4800, 256, 0, stream>>>(Whh0, Whh, whh16);

  // layer 0: A0 -> Xa
  for (int c = 0; c < 1024 / CT; ++c) {
    gemm_chunk<<<dim3(5, 128), 256, 0, stream>>>(A0, Wt0, gxc, in_lens, 128, 4, c);
    lstm_scan_chunk<<<256, 512, 0, stream>>>(whh16, gxc, b0, in_lens, Xa, xq,
                                             hsave, csave, 0, c);
  }
  // layer 1: Xa -> Xb
  for (int c = 0; c < 1024 / CT; ++c) {
    gemm_chunk<<<dim3(5, 128), 256, 0, stream>>>(Xa, Wt12, gxc, in_lens, 640, 20, c);
    lstm_scan_chunk<<<256, 512, 0, stream>>>(whh16, gxc, bb, in_lens, Xb, xq,
                                             hsave, csave, 1, c);
  }
  // layer 2: Xb -> Xa
  for (int c = 0; c < 1024 / CT; ++c) {
    gemm_chunk<<<dim3(5, 128), 256, 0, stream>>>(Xb, Wt12 + (size_t)2560 * 640, gxc,
                                                 in_lens, 640, 20, c);
    lstm_scan_chunk<<<256, 512, 0, stream>>>(whh16, gxc, bb + 2560, in_lens, Xa, xq,
                                             hsave, csave, 2, c);
  }
  // projection: Xa -> Z (f32)
  gemm_proj<<<dim3(1, 512), 256, 0, stream>>>(Xa, WtL, Z, 640, 20, 128);

  lse_kernel<<<16384, 256, 0, stream>>>(Z, b_lin, lseb);
  emz_kernel<<<dim3(256, 64), 256, 0, stream>>>(Z, lseb, b_lin, labels, emc);
  ctc_kernel<<<64, 64, 0, stream>>>(emc, labels, in_lens, lab_lens, num);
  final_kernel<<<1, 64, 0, stream>>>(num, (float*)d_out);
}

// Round 6
// 9102.285 us; speedup vs baseline: 1.4289x; 1.0317x over previous
//
#include <hip/hip_runtime.h>
#include <cstdint>
#include <cstddef>

// ---------------------------------------------------------------------------
// CTC-CRF BLSTM pipeline for MI355X.  B=64 T=1024 IDIM=120 HDIM=320 K=72
// den == 0 analytically; batch sort is a no-op under the batch mean. Skipped.
//
// R14 deltas vs R13 (9.39 ms; poll3 null):
//  - Diagnosis: __hip_atomic_load(AGENT) drains vmcnt(0) per load, so R13's
//    "3-deep pipeline" was serialized by the compiler: one MALL RT (~2100cy)
//    per sample. Sample 1 issues at gates-start and passes the MALL ~700cy
//    after publish -- just BEFORE the partner's store lands (transit
//    ~600-1400cy) -> stale -> sample 2 lands at +3900..4300cy. Matches the
//    measured ~4350cy exchange exposure exactly.
//  - Fix: staggered-sample poll in RAW ASM: 4 system-scope loads spaced by
//    s_sleep 4 (~256cy, 768cy spread), drained with counted s_waitcnt
//    vmcnt(3..0). One of samples 1-3 passes the MALL after the store lands,
//    returning at ~T_pub+2100-2900 instead of +4350. Single-exit (all waits
//    always execute) so no in-flight load can land in a reused register.
//    Serial agent-scope fallback retained for correctness.
// ---------------------------------------------------------------------------

typedef _Float16 f16;
typedef _Float16 h2v   __attribute__((ext_vector_type(2)));
typedef _Float16 f16x4v __attribute__((ext_vector_type(4)));
typedef _Float16 f16x8 __attribute__((ext_vector_type(8)));
typedef float    f32x4 __attribute__((ext_vector_type(4)));
typedef uint32_t u32x4 __attribute__((ext_vector_type(4)));

#define NEGF (-1e30f)
#define CT 128

__device__ __forceinline__ float dot2f(h2v a, h2v b, float c) {
#if __has_builtin(__builtin_amdgcn_fdot2)
  return __builtin_amdgcn_fdot2(a, b, c, false);
#else
  return c + (float)a.x * (float)b.x + (float)a.y * (float)b.y;
#endif
}

__device__ __forceinline__ float fast_rcp(float x) {
#if __has_builtin(__builtin_amdgcn_rcpf)
  return __builtin_amdgcn_rcpf(x);
#else
  return 1.f / x;
#endif
}
__device__ __forceinline__ float fsigm(float x) { return fast_rcp(1.f + __expf(-x)); }
__device__ __forceinline__ float ftanh(float x) { return 1.f - 2.f * fast_rcp(1.f + __expf(2.f * x)); }

__device__ __forceinline__ float fexp2(float x) {
#if __has_builtin(__builtin_amdgcn_exp2f)
  return __builtin_amdgcn_exp2f(x);
#else
  return exp2f(x);
#endif
}
__device__ __forceinline__ float flog2(float x) {
#if __has_builtin(__builtin_amdgcn_logf)
  return __builtin_amdgcn_logf(x);
#else
  return log2f(x);
#endif
}

// Staggered-sample exchange poll. 4 system-scope loads of the same slot,
// spaced ~256cy; counted vmcnt drains; single exit (all 4 waits always
// execute so no pending load can clobber a reused VGPR). Tags are monotone
// and the partner can never run a full step ahead, so any matching sample is
// the wanted value. Serial agent-scope fallback for the rare full miss.
__device__ __forceinline__ uint32_t poll_stag(const uint32_t* p, uint32_t tag) {
  uint32_t p0, p1, p2, p3;
  asm volatile(
      "global_load_dword %0, %4, off sc0 sc1\n\t"
      "s_sleep 4\n\t"
      "global_load_dword %1, %4, off sc0 sc1\n\t"
      "s_sleep 4\n\t"
      "global_load_dword %2, %4, off sc0 sc1\n\t"
      "s_sleep 4\n\t"
      "global_load_dword %3, %4, off sc0 sc1"
      : "=&v"(p0), "=&v"(p1), "=&v"(p2), "=&v"(p3)
      : "v"(p)
      : "memory");
  uint32_t pw = 0;
  bool got = false;
  asm volatile("s_waitcnt vmcnt(3)" : "+v"(p0)::"memory");
  if ((p0 >> 16) == tag) { pw = p0; got = true; }
  asm volatile("s_waitcnt vmcnt(2)" : "+v"(p1)::"memory");
  if (!got && (p1 >> 16) == tag) { pw = p1; got = true; }
  asm volatile("s_waitcnt vmcnt(1)" : "+v"(p2)::"memory");
  if (!got && (p2 >> 16) == tag) { pw = p2; got = true; }
  asm volatile("s_waitcnt vmcnt(0)" : "+v"(p3)::"memory");
  if (!got && (p3 >> 16) == tag) { pw = p3; got = true; }
  if (!got) {
    int spins = 0;
    do {
      pw = __hip_atomic_load((const volatile uint32_t*)p, __ATOMIC_RELAXED,
                             __HIP_MEMORY_SCOPE_AGENT);
    } while ((pw >> 16) != tag && ++spins < 200000);
  }
  return pw;
}

__device__ __forceinline__ void stage16(f16* lds, const f16* g) {
#if __has_builtin(__builtin_amdgcn_global_load_lds)
  __builtin_amdgcn_global_load_lds(
      (const __attribute__((address_space(1))) uint32_t*)g,
      (__attribute__((address_space(3))) uint32_t*)lds, 16, 0, 0);
#else
  int lane = threadIdx.x & 63;
  *(f16x8*)&lds[lane * 8] = *(const f16x8*)g;
#endif
}

// ---------------------------- convert kernels ------------------------------

__global__ void conv_logits(const float* __restrict__ src, f16* __restrict__ dst) {
  int idx = blockIdx.x * 256 + threadIdx.x;      // < 65536*128
  int row = idx >> 7, k = idx & 127;
  dst[idx] = (f16)((k < 120) ? src[(size_t)row * 120 + k] : 0.f);
}

__global__ void conv_wt0(const float* __restrict__ w, f16* __restrict__ dst) {
  int idx = blockIdx.x * 256 + threadIdx.x;      // < 2560*128
  int n = idx >> 7, k = idx & 127;
  dst[idx] = (f16)((k < 120) ? w[(size_t)n * 120 + k] : 0.f);
}

__global__ void conv_copy(const float* __restrict__ src, f16* __restrict__ dst, int count) {
  int idx = blockIdx.x * 256 + threadIdx.x;
  if (idx < count) dst[idx] = (f16)src[idx];
}

__global__ void conv_wtl(const float* __restrict__ w, f16* __restrict__ dst) {
  int idx = blockIdx.x * 256 + threadIdx.x;      // < 128*640
  int n = idx / 640, k = idx % 640;
  dst[idx] = (f16)((n < 72) ? w[(size_t)n * 640 + k] : 0.f);
}

// Whh -> pair-packed scan layout (same as R6/R7).
__global__ void conv_whh(const float* __restrict__ whh0, const float* __restrict__ whh,
                         uint32_t* __restrict__ dst) {
  int o = blockIdx.x * 256 + threadIdx.x;        // < 6*2*200*512 = 1228800
  int tid = o & 511;
  int g  = o >> 9;
  int j  = g % 40;
  int g2 = g / 40;
  int i  = g2 % 5;
  int g3 = g2 / 5;                               // 0..11
  int hf = g3 & 1, slot = g3 >> 1;               // slot = layer*2+dir
  int tau = i * 512 + tid;
  int lr = tau >> 2, kq = tau & 3;
  int gate = lr / 160, u = lr - gate * 160;
  int r = gate * 320 + hf * 160 + u;
  int k = kq * 80 + j * 2;
  const float* srcm = (slot < 2) ? (whh0 + ((size_t)slot * 1280 + r) * 320)
                                 : (whh  + ((size_t)(slot - 2) * 1280 + r) * 320);
  f16 lo = (f16)srcm[k], hi = (f16)srcm[k + 1];
  dst[o] = (uint32_t)__builtin_bit_cast(unsigned short, lo) |
           ((uint32_t)__builtin_bit_cast(unsigned short, hi) << 16);
}

// --------------------- gather-GEMM for one time chunk ----------------------
__global__ __launch_bounds__(256)
void gemm_chunk(const f16* __restrict__ A, const f16* __restrict__ W,
                f16* __restrict__ gxc, const int* __restrict__ lens,
                int lda, int kTiles, int c0) {
  __shared__ __align__(16) f16 As[128 * 32];
  __shared__ __align__(16) f16 Ws[2][128 * 32];
  const int tid = threadIdx.x;
  const int lane = tid & 63, wid = tid >> 6;
  const int wm = wid >> 1, wn = wid & 1;
  const int dir = blockIdx.y >> 6, b = blockIdx.y & 63;
  const int n0 = blockIdx.x * 256;
  const int r_base = lane >> 2;                              // 0..15
  const int chs = ((((lane & 3) + (r_base >> 1)) & 3)) * 8;  // swizzled SRC k-chunk
  const int len = lens[b];

  f32x4 acc[4][8] = {};

  for (int kt = 0; kt < kTiles; ++kt) {
    const int k0 = kt * 32;
    __syncthreads();
#pragma unroll
    for (int hh = 0; hh < 2; ++hh) {
      const int c = wid * 2 + hh;
      const int j = c * 16 + r_base;                     // step within chunk
      const int s = c0 * CT + j;
      const int tt = dir ? ((s < len) ? (len - 1 - s) : s) : s;
      stage16(&As[c * 512], A + (size_t)(b * 1024 + tt) * lda + k0 + chs);
    }
#pragma unroll
    for (int hh = 0; hh < 4; ++hh) {
      const int c = wid * 4 + hh;                        // 0..15
      const int tile = c >> 3, cc = c & 7;
      stage16(&Ws[tile][cc * 512],
              W + (size_t)(dir * 1280 + n0 + tile * 128 + cc * 16 + r_base) * lda + k0 + chs);
    }
    __syncthreads();

    const int q = lane >> 4;                 // MFMA k-chunk
    const int l15 = lane & 15;
    const int cs = (q - (l15 >> 1)) & 3;     // swizzled slot holding chunk q
    const int rofs = l15 * 32 + cs * 8;      // f16 units within a 16-row chunk
    f16x8 av[4], wv0[4], wv1[4];
#pragma unroll
    for (int i = 0; i < 4; ++i)
      av[i] = *(const f16x8*)&As[(wm * 4 + i) * 512 + rofs];
#pragma unroll
    for (int i = 0; i < 4; ++i) {
      wv0[i] = *(const f16x8*)&Ws[0][(wn * 4 + i) * 512 + rofs];
      wv1[i] = *(const f16x8*)&Ws[1][(wn * 4 + i) * 512 + rofs];
    }
#pragma unroll
    for (int i = 0; i < 4; ++i)
#pragma unroll
      for (int j = 0; j < 4; ++j) {
        acc[i][j]     = __builtin_amdgcn_mfma_f32_16x16x32_f16(av[i], wv0[j], acc[i][j], 0, 0, 0);
        acc[i][4 + j] = __builtin_amdgcn_mfma_f32_16x16x32_f16(av[i], wv1[j], acc[i][4 + j], 0, 0, 0);
      }
  }

  const int r0 = (lane >> 4) * 4, cn = lane & 15;
  const size_t obase = (size_t)(dir * 64 + b) * CT;
#pragma unroll
  for (int i = 0; i < 4; ++i) {
    const int m = wm * 64 + i * 16 + r0;
#pragma unroll
    for (int j = 0; j < 4; ++j) {
      const int n = n0 + wn * 64 + j * 16 + cn;
#pragma unroll
      for (int r = 0; r < 4; ++r) {
        gxc[(obase + m + r) * 1280 + n]       = (f16)acc[i][j][r];
        gxc[(obase + m + r) * 1280 + n + 128] = (f16)acc[i][4 + j][r];
      }
    }
  }
}

// ------------------------- LSTM scan (one chunk) ---------------------------
// R8 structure: 256 WGs, one (b,dir,half) stream each; agent-scope exchange.
// R14: consumer uses the staggered-sample raw-asm poll.
__global__ void __launch_bounds__(512)
__attribute__((amdgpu_waves_per_eu(2, 2)))
lstm_scan_chunk(const volatile uint32_t* wbuf,      // NOT restrict: may alias
                const f16* __restrict__ gxc,        // [2*64*CT][1280]
                const float* __restrict__ bias,     // [2][1280] this layer
                const int* __restrict__ lens,
                f16* xnext,                         // [65536][640] (no restrict)
                uint32_t* xq,                       // [512][160] tagged words
                f16* hsave,                         // [128][320]
                float* csave,                       // [256][160]
                int layer, int c0) {
  const int wg = blockIdx.x;
  const int half = wg >> 7;
  const int bd = wg & 127;
  const int b = bd >> 1, dir = bd & 1;
  const int tid = threadIdx.x;

  __shared__ __align__(16) f16 hbuf[320];
  __shared__ float ylds[640];
  __shared__ __align__(16) f16 hstage[64 * 160];   // 20 KB ring

  h2v w[5][40];
  {
    const volatile uint32_t* wb =
        wbuf + (size_t)((layer * 2 + dir) * 2 + half) * 200 * 512;
#pragma unroll
    for (int i = 0; i < 5; ++i)
#pragma unroll
      for (int j = 0; j < 40; ++j) {
        uint32_t v = wb[(i * 40 + j) * 512 + tid];
        w[i][j] = __builtin_bit_cast(h2v, v);
      }
  }
  if (tid < 320) hbuf[tid] = (c0 == 0) ? (f16)0.f : hsave[bd * 320 + tid];

  const int len = lens[b];
  const int kq = tid & 3;
  const int qi = tid >> 2;
  const int gu = half * 160 + tid;               // valid when tid<160
  float c_state = 0.f;
  float bi = 0.f, bff = 0.f, bg = 0.f, bo = 0.f;
  if (tid < 160) {
    if (c0 > 0) c_state = csave[wg * 160 + tid];
    const float* bp = bias + dir * 1280 + gu;
    bi = bp[0]; bff = bp[320]; bg = bp[640]; bo = bp[960];
  }
  __syncthreads();

  const size_t grow0 = (size_t)(dir * 64 + b) * CT;

  float gxi = 0.f, gxf = 0.f, gxg = 0.f, gxo = 0.f;
  if (tid < 160) {
    const f16* gp = gxc + grow0 * 1280 + gu;
    gxi = (float)gp[0]; gxf = (float)gp[320]; gxg = (float)gp[640]; gxo = (float)gp[960];
  }

  for (int tl = 0; tl < CT; ++tl) {
    const int s = c0 * CT + tl;
    const uint32_t tag = (uint32_t)(layer * 1024 + s + 1);

    float nxi = 0.f, nxf = 0.f, nxg = 0.f, nxo = 0.f;
    if (tid < 160 && tl + 1 < CT) {
      const f16* gp = gxc + (grow0 + tl + 1) * 1280 + gu;
      nxi = (float)gp[0]; nxf = (float)gp[320]; nxg = (float)gp[640]; nxo = (float)gp[960];
    }

    // ---- y = Whh_half . h  (all threads, b128 LDS reads; broadcast-free) ----
    float a0 = 0.f, a1 = 0.f, a2 = 0.f, a3 = 0.f, a4 = 0.f;
    {
      const u32x4* h4 = (const u32x4*)hbuf;
#pragma unroll
      for (int jb = 0; jb < 5; ++jb) {
        u32x4 p = h4[kq * 10 + jb * 2];
        u32x4 q = h4[kq * 10 + jb * 2 + 1];
        h2v hr[8];
#pragma unroll
        for (int j = 0; j < 4; ++j) hr[j] = __builtin_bit_cast(h2v, p[j]);
#pragma unroll
        for (int j = 0; j < 4; ++j) hr[4 + j] = __builtin_bit_cast(h2v, q[j]);
#pragma unroll
        for (int j = 0; j < 8; ++j) {
          a0 = dot2f(w[0][jb * 8 + j], hr[j], a0);
          a1 = dot2f(w[1][jb * 8 + j], hr[j], a1);
          a2 = dot2f(w[2][jb * 8 + j], hr[j], a2);
          a3 = dot2f(w[3][jb * 8 + j], hr[j], a3);
          a4 = dot2f(w[4][jb * 8 + j], hr[j], a4);
        }
      }
    }
    {
      float av[5] = {a0, a1, a2, a3, a4};
#pragma unroll
      for (int i = 0; i < 5; ++i) {
        float v = av[i];
        v += __shfl_xor(v, 1, 64);
        v += __shfl_xor(v, 2, 64);
        if (kq == 0) ylds[i * 128 + qi] = v;
      }
    }

    if ((tl & 31) == 0 && tl > 0) {
      const int tw = tl - 32;
#pragma unroll
      for (int it = 0; it < 2; ++it) {
        const int slot = it * 512 + tid;
        if (slot < 640) {
          const int r = (int)(((unsigned)slot * 52429u) >> 20);  // slot/20
          const int j = slot - r * 20;
          const int sp = c0 * CT + tw + r;
          const int ttp = dir ? ((sp < len) ? (len - 1 - sp) : sp) : sp;
          f16x8 v = *(const f16x8*)&hstage[((tw + r) & 63) * 160 + j * 8];
          *(f16x8*)&xnext[(size_t)(b * 1024 + ttp) * 640 + dir * 320 + half * 160 + j * 8] = v;
        }
      }
    }
    __syncthreads();                              // B1: ylds ready

    if (tid < 160) {
      const int u = tid;
      float pi = ylds[u]       + gxi + bi;
      float pf = ylds[160 + u] + gxf + bff;
      float pg = ylds[320 + u] + gxg + bg;
      float po = ylds[480 + u] + gxo + bo;
      float ig = fsigm(pi);
      float fg = fsigm(pf);
      float gg = ftanh(pg);
      float og = fsigm(po);
      c_state = fg * c_state + ig * gg;
      float hv = og * ftanh(c_state);
      const f16 hh = (f16)hv;
      const uint32_t word = (tag << 16) |
                            (uint32_t)__builtin_bit_cast(unsigned short, hh);
      __hip_atomic_store(&xq[((bd * 2 + half) * 2 + (s & 1)) * 160 + u], word,
                         __ATOMIC_RELAXED, __HIP_MEMORY_SCOPE_AGENT);
      hbuf[gu] = hh;
      hstage[(tl & 63) * 160 + u] = hh;
    } else if (tid >= 256 && tid < 416) {
      const int u = tid - 256;
      const uint32_t pw =
          poll_stag(&xq[((bd * 2 + (1 - half)) * 2 + (s & 1)) * 160 + u], tag);
      hbuf[(1 - half) * 160 + u] =
          __builtin_bit_cast(f16, (unsigned short)(pw & 0xffffu));
    }
    __syncthreads();                              // B2: hbuf ready for next dot

    gxi = nxi; gxf = nxf; gxg = nxg; gxo = nxo;
  }

  {
    const int tw = CT - 32;
#pragma unroll
    for (int it = 0; it < 2; ++it) {
      const int slot = it * 512 + tid;
      if (slot < 640) {
        const int r = (int)(((unsigned)slot * 52429u) >> 20);
        const int j = slot - r * 20;
        const int sp = c0 * CT + tw + r;
        const int ttp = dir ? ((sp < len) ? (len - 1 - sp) : sp) : sp;
        f16x8 v = *(const f16x8*)&hstage[((tw + r) & 63) * 160 + j * 8];
        *(f16x8*)&xnext[(size_t)(b * 1024 + ttp) * 640 + dir * 320 + half * 160 + j * 8] = v;
      }
    }
  }
  if (tid < 160) {
    hsave[bd * 320 + gu] = hbuf[gu];
    csave[wg * 160 + tid] = c_state;
  }
}

// ---------------------- projection GEMM (f32 out) --------------------------
__global__ __launch_bounds__(256)
void gemm_proj(const f16* __restrict__ A, const f16* __restrict__ W,
               float* __restrict__ outf, int lda, int kTiles, int ldo) {
  __shared__ __align__(16) f16 As[128 * 32];
  __shared__ __align__(16) f16 Ws[128 * 32];
  const int tid = threadIdx.x;
  const int lane = tid & 63, wid = tid >> 6;
  const int wm = wid >> 1, wn = wid & 1;
  const int m0 = blockIdx.y * 128, n0 = blockIdx.x * 128;
  const int r_base = lane >> 2;
  const int chs = ((((lane & 3) + (r_base >> 1)) & 3)) * 8;  // swizzled SRC chunk

  f32x4 acc[4][4] = {};

  for (int kt = 0; kt < kTiles; ++kt) {
    const int k0 = kt * 32;
    __syncthreads();
#pragma unroll
    for (int hh = 0; hh < 2; ++hh) {
      const int c = wid * 2 + hh;
      stage16(&As[c * 512], A + (size_t)(m0 + c * 16 + r_base) * lda + k0 + chs);
      stage16(&Ws[c * 512], W + (size_t)(n0 + c * 16 + r_base) * lda + k0 + chs);
    }
    __syncthreads();

    const int q = lane >> 4;
    const int l15 = lane & 15;
    const int cs = (q - (l15 >> 1)) & 3;
    const int rofs = l15 * 32 + cs * 8;
    f16x8 av[4], wv[4];
#pragma unroll
    for (int i = 0; i < 4; ++i)
      av[i] = *(const f16x8*)&As[(wm * 4 + i) * 512 + rofs];
#pragma unroll
    for (int i = 0; i < 4; ++i)
      wv[i] = *(const f16x8*)&Ws[(wn * 4 + i) * 512 + rofs];
#pragma unroll
    for (int i = 0; i < 4; ++i)
#pragma unroll
      for (int j = 0; j < 4; ++j)
        acc[i][j] = __builtin_amdgcn_mfma_f32_16x16x32_f16(av[i], wv[j], acc[i][j], 0, 0, 0);
  }

  const int r0 = (lane >> 4) * 4, cn = lane & 15;
#pragma unroll
  for (int i = 0; i < 4; ++i) {
    const int m = m0 + wm * 64 + i * 16 + r0;
#pragma unroll
    for (int j = 0; j < 4; ++j) {
      const int n = n0 + wn * 64 + j * 16 + cn;
#pragma unroll
      for (int r = 0; r < 4; ++r)
        outf[(size_t)(m + r) * ldo + n] = acc[i][j][r];
    }
  }
}

// ------------------------- logsumexp over K=72 ------------------------------
__global__ void lse_kernel(const float* __restrict__ Z, const float* __restrict__ b_lin,
                           float* __restrict__ lseout) {
  int row = blockIdx.x * 4 + (threadIdx.x >> 6);
  int l = threadIdx.x & 63;
  const float* z = Z + (size_t)row * 128;
  float v0 = (l < 72) ? z[l] + b_lin[l] : NEGF;
  float v1 = (l < 8) ? z[l + 64] + b_lin[l + 64] : NEGF;
  float m = fmaxf(v0, v1);
#pragma unroll
  for (int o = 32; o; o >>= 1) m = fmaxf(m, __shfl_xor(m, o, 64));
  float s = ((l < 72) ? __expf(v0 - m) : 0.f) + ((l < 8) ? __expf(v1 - m) : 0.f);
#pragma unroll
  for (int o = 32; o; o >>= 1) s += __shfl_xor(s, o, 64);
  if (l == 0) lseout[row] = m + __logf(s);
}

// --------------- emission pre-gather: emc[b][t][s] (f16) -------------------
// emc = (Z[t][ext[s]] + b_lin[ext[s]] - lse[t]) * log2(e).  Base-2 domain so
// the ctc recursion uses raw v_exp_f32 / v_log_f32.
__global__ void emz_kernel(const float* __restrict__ Z, const float* __restrict__ lse,
                           const float* __restrict__ b_lin,
                           const int* __restrict__ labels,
                           f16* __restrict__ emc) {
  const int b = blockIdx.y;
  const int t0 = blockIdx.x * 4;
  const int tid = threadIdx.x;   // 256
  __shared__ int ext[200];
  __shared__ float bls[200];
  if (tid < 200) {
    int e = (tid < 193 && (tid & 1)) ? labels[b * 96 + (tid >> 1)] : 0;
    ext[tid] = e;
    bls[tid] = b_lin[e];
  }
  __syncthreads();
#pragma unroll
  for (int dt = 0; dt < 4; ++dt) {
    const int t = t0 + dt;
    const float lst = lse[b * 1024 + t];
    const float* zr = Z + ((size_t)(b * 1024 + t)) * 128;
    for (int s = tid; s < 200; s += 256)
      emc[((size_t)(b * 1024 + t)) * 200 + s] =
          (f16)((zr[ext[s]] + bls[s] - lst) * 1.4426950408889634f);
  }
}

// ------------------------------ CTC forward ---------------------------------
__global__ void ctc_kernel(const f16* __restrict__ emc,
                           const int* __restrict__ labels, const int* __restrict__ inlen,
                           const int* __restrict__ lablen, float* __restrict__ num) {
  const int b = blockIdx.x;
  const int lane = threadIdx.x;          // 64
  __shared__ int ext[200];
  __shared__ float afin[200];

  for (int s = lane; s < 200; s += 64)
    ext[s] = (s < 193 && (s & 1)) ? labels[b * 96 + (s >> 1)] : 0;
  __syncthreads();

  const int L = lablen[b], len = inlen[b];
  const int Send = 2 * L + 1;
  const f16* eb = emc + (size_t)b * 1024 * 200;

  float a[4];
  bool  skp[4], val[4];
#pragma unroll
  for (int j = 0; j < 4; ++j) {
    const int s = lane * 4 + j;
    val[j] = (s < Send) && (s < 193);
    skp[j] = (s < 193) && (s & 1) && (s >= 2) && (ext[s] != ext[s - 2]);
  }
  {
    f16x4v e0 = *(const f16x4v*)&eb[lane * 4];   // t = 0
#pragma unroll
    for (int j = 0; j < 4; ++j) {
      const int s = lane * 4 + j;
      a[j] = (s <= 1 && val[j]) ? (float)e0[j] : NEGF;
    }
  }

  auto step = [&](f16x4v ev) {
    float p3 = __shfl_up(a[3], 1, 64);
    float p2 = __shfl_up(a[2], 1, 64);
    if (lane == 0) { p3 = NEGF; p2 = NEGF; }
    const float x2[4] = {p3, a[0], a[1], a[2]};
    const float x3[4] = {p2, p3, a[0], a[1]};
#pragma unroll
    for (int j = 0; j < 4; ++j) {
      const float xa = a[j], xb = x2[j];
      const float xc = skp[j] ? x3[j] : NEGF;
      const float m = fmaxf(xa, fmaxf(xb, xc));
      const float sum = fexp2(xa - m) + fexp2(xb - m) + fexp2(xc - m);
      const float nv = m + flog2(sum) + (float)ev[j];
      a[j] = val[j] ? nv : NEGF;
    }
  };

  // depth-8 register ring, fully static slot indexing
  f16x4v ring[8];
#pragma unroll
  for (int d = 1; d <= 8; ++d) {
    const int r = (d < len) ? d : (len - 1);
    ring[d & 7] = *(const f16x4v*)&eb[(size_t)r * 200 + lane * 4];
  }

  int t = 1;
  for (; t + 8 <= len; t += 8) {
#pragma unroll
    for (int k = 0; k < 8; ++k) {
      const int slot = (1 + k) & 7;        // t == 1 (mod 8)
      f16x4v ev = ring[slot];
      const int tp = t + k + 8;
      if (tp < len)
        ring[slot] = *(const f16x4v*)&eb[(size_t)tp * 200 + lane * 4];
      step(ev);
    }
  }
  for (; t < len; ++t)
    step(*(const f16x4v*)&eb[(size_t)t * 200 + lane * 4]);

#pragma unroll
  for (int j = 0; j < 4; ++j) {
    const int s = lane * 4 + j;
    if (s < 193) afin[s] = a[j];
  }
  __syncthreads();
  if (lane == 0) {
    const float aL = afin[2 * L], aLm1 = afin[2 * L - 1];
    const float m = fmaxf(aL, aLm1);
    // back to natural log for the final reduction
    num[b] = 0.6931471805599453f * (m + flog2(fexp2(aL - m) + fexp2(aLm1 - m)));
  }
}

__global__ void final_kernel(const float* __restrict__ num, float* __restrict__ out) {
  int l = threadIdx.x;  // 64
  float v = -1.1f * num[l];
#pragma unroll
  for (int o = 32; o; o >>= 1) v += __shfl_xor(v, o, 64);
  if (l == 0) out[0] = v * (1.f / 64.f);
}

__global__ void sentinel_kernel(float* __restrict__ out, float code) { out[0] = code; }

// ------------------------------ launcher ------------------------------------
extern "C" void kernel_launch(void* const* d_in, const int* in_sizes, int n_in,
                              void* d_out, int out_size, void* d_ws, size_t ws_size,
                              hipStream_t stream) {
  (void)in_sizes; (void)n_in; (void)out_size;

  const float* logits   = (const float*)d_in[0];
  const int*   labels   = (const int*)d_in[1];
  const int*   in_lens  = (const int*)d_in[2];
  const int*   lab_lens = (const int*)d_in[3];
  const float* Wih0     = (const float*)d_in[4];
  const float* Whh0     = (const float*)d_in[5];
  const float* b0       = (const float*)d_in[6];
  const float* Wih      = (const float*)d_in[7];
  const float* Whh      = (const float*)d_in[8];
  const float* bb       = (const float*)d_in[9];
  const float* W_lin    = (const float*)d_in[10];
  const float* b_lin    = (const float*)d_in[11];

  const size_t NEED = (size_t)224 * 1024 * 1024;
  if (ws_size < NEED) {
    sentinel_kernel<<<1, 1, 0, stream>>>((float*)d_out, -(float)(ws_size >> 20));
    return;
  }

  char* ws = (char*)d_ws;
  size_t off = 0;
  auto alloc = [&](size_t bytes) -> char* {
    char* p = ws + off;
    off += (bytes + 255) & ~(size_t)255;
    return p;
  };
  f16*      Xa     = (f16*)alloc((size_t)65536 * 640 * 2);        // 83.9 MB
  f16*      Xb     = (f16*)alloc((size_t)65536 * 640 * 2);        // 83.9 MB
  f16*      gxc    = (f16*)alloc((size_t)2 * 64 * CT * 1280 * 2); // 41.9 MB
  f16*      Wt0    = (f16*)alloc((size_t)2560 * 128 * 2);
  f16*      Wt12   = (f16*)alloc((size_t)2 * 2560 * 640 * 2);
  f16*      WtL    = (f16*)alloc((size_t)128 * 640 * 2);
  uint32_t* whh16  = (uint32_t*)alloc((size_t)6 * 2 * 200 * 512 * 4);
  float*    lseb   = (float*)alloc((size_t)65536 * 4);
  float*    num    = (float*)alloc(64 * 4);
  uint32_t* xq     = (uint32_t*)alloc((size_t)512 * 160 * 4);
  f16*      hsave  = (f16*)alloc((size_t)128 * 320 * 2);
  float*    csave  = (float*)alloc((size_t)256 * 160 * 4);
  // aliases (disjoint lifetimes)
  f16*      A0     = Xb;           // dead after layer 0; Xb first written layer 1
  float*    Z      = (float*)gxc;  // gxc dead after layer-2 scan
  f16*      emc    = Xa;           // Xa dead after gemm_proj

  hipMemsetAsync(xq, 0, (size_t)512 * 160 * 4, stream);

  conv_logits<<<32768, 256, 0, stream>>>(logits, A0);
  conv_wt0<<<1280, 256, 0, stream>>>(Wih0, Wt0);
  conv_copy<<<12800, 256, 0, stream>>>(Wih, Wt12, 3276800);
  conv_wtl<<<320, 256, 0, stream>>>(W_lin, WtL);
  conv_whh<<<4800, 256, 0, stream>>>(Whh0, Whh, whh16);

  // layer 0: A0 -> Xa
  for (int c = 0; c < 1024 / CT; ++c) {
    gemm_chunk<<<dim3(5, 128), 256, 0, stream>>>(A0, Wt0, gxc, in_lens, 128, 4, c);
    lstm_scan_chunk<<<256, 512, 0, stream>>>(whh16, gxc, b0, in_lens, Xa, xq,
                                             hsave, csave, 0, c);
  }
  // layer 1: Xa -> Xb
  for (int c = 0; c < 1024 / CT; ++c) {
    gemm_chunk<<<dim3(5, 128), 256, 0, stream>>>(Xa, Wt12, gxc, in_lens, 640, 20, c);
    lstm_scan_chunk<<<256, 512, 0, stream>>>(whh16, gxc, bb, in_lens, Xb, xq,
                                             hsave, csave, 1, c);
  }
  // layer 2: Xb -> Xa
  for (int c = 0; c < 1024 / CT; ++c) {
    gemm_chunk<<<dim3(5, 128), 256, 0, stream>>>(Xb, Wt12 + (size_t)2560 * 640, gxc,
                                                 in_lens, 640, 20, c);
    lstm_scan_chunk<<<256, 512, 0, stream>>>(whh16, gxc, bb + 2560, in_lens, Xa, xq,
                                             hsave, csave, 2, c);
  }
  // projection: Xa -> Z (f32)
  gemm_proj<<<dim3(1, 512), 256, 0, stream>>>(Xa, WtL, Z, 640, 20, 128);

  lse_kernel<<<16384, 256, 0, stream>>>(Z, b_lin, lseb);
  emz_kernel<<<dim3(256, 64), 256, 0, stream>>>(Z, lseb, b_lin, labels, emc);
  ctc_kernel<<<64, 64, 0, stream>>>(emc, labels, in_lens, lab_lens, num);
  final_kernel<<<1, 64, 0, stream>>>(num, (float*)d_out);
}

// Round 7
// 8893.125 us; speedup vs baseline: 1.4625x; 1.0235x over previous
//
#include <hip/hip_runtime.h>
#include <cstdint>
#include <cstddef>

// ---------------------------------------------------------------------------
// CTC-CRF BLSTM pipeline for MI355X.  B=64 T=1024 IDIM=120 HDIM=320 K=72
// den == 0 analytically; batch sort is a no-op under the batch mean. Skipped.
//
// R15 deltas vs R14 (9.10 ms; 6 consecutive exchange-primitive nulls):
//  - Re-diagnosis: every poll/store primitive change was null -> the ~4K
//    cy/step stall is NOT the exchange path. The untouched cost: each
//    __syncthreads compiles to s_waitcnt vmcnt(0) lgkmcnt(0) + s_barrier.
//    Two per step force full retirement of the MALL publish store (~1-1.5K
//    cy), poll loads, and gxc prefetches INSIDE the step instead of hiding
//    them under the next dot.
//  - Fix: in-loop barriers are now raw `s_waitcnt lgkmcnt(0)` + s_barrier
//    (LDS-only fence; B1 guards ylds, B2 guards hbuf -- both LDS). The
//    publish store needs no local drain (remote consumer; MALL arrival
//    governs visibility); gxc loads get compiler waits at use; xnext
//    flushes are consumed by later kernels (end-of-kernel drain).
//  - Poll reverted to the simple serial agent load (R8-proven; all fancier
//    variants measured equal).
// ---------------------------------------------------------------------------

typedef _Float16 f16;
typedef _Float16 h2v   __attribute__((ext_vector_type(2)));
typedef _Float16 f16x4v __attribute__((ext_vector_type(4)));
typedef _Float16 f16x8 __attribute__((ext_vector_type(8)));
typedef float    f32x4 __attribute__((ext_vector_type(4)));
typedef uint32_t u32x4 __attribute__((ext_vector_type(4)));

#define NEGF (-1e30f)
#define CT 128

__device__ __forceinline__ float dot2f(h2v a, h2v b, float c) {
#if __has_builtin(__builtin_amdgcn_fdot2)
  return __builtin_amdgcn_fdot2(a, b, c, false);
#else
  return c + (float)a.x * (float)b.x + (float)a.y * (float)b.y;
#endif
}

__device__ __forceinline__ float fast_rcp(float x) {
#if __has_builtin(__builtin_amdgcn_rcpf)
  return __builtin_amdgcn_rcpf(x);
#else
  return 1.f / x;
#endif
}
__device__ __forceinline__ float fsigm(float x) { return fast_rcp(1.f + __expf(-x)); }
__device__ __forceinline__ float ftanh(float x) { return 1.f - 2.f * fast_rcp(1.f + __expf(2.f * x)); }

__device__ __forceinline__ float fexp2(float x) {
#if __has_builtin(__builtin_amdgcn_exp2f)
  return __builtin_amdgcn_exp2f(x);
#else
  return exp2f(x);
#endif
}
__device__ __forceinline__ float flog2(float x) {
#if __has_builtin(__builtin_amdgcn_logf)
  return __builtin_amdgcn_logf(x);
#else
  return log2f(x);
#endif
}

// LDS-only barrier: orders LDS ops across the workgroup WITHOUT draining
// vmcnt (the compiler's __syncthreads emits s_waitcnt vmcnt(0), forcing the
// MALL publish store + prefetch loads to retire inside the step). The asm
// memory clobber + sched_barrier(0) pin compiler-level ordering (rule #18).
__device__ __forceinline__ void bar_lds() {
  __builtin_amdgcn_sched_barrier(0);
  asm volatile("s_waitcnt lgkmcnt(0)" ::: "memory");
  __builtin_amdgcn_s_barrier();
  __builtin_amdgcn_sched_barrier(0);
}

__device__ __forceinline__ void stage16(f16* lds, const f16* g) {
#if __has_builtin(__builtin_amdgcn_global_load_lds)
  __builtin_amdgcn_global_load_lds(
      (const __attribute__((address_space(1))) uint32_t*)g,
      (__attribute__((address_space(3))) uint32_t*)lds, 16, 0, 0);
#else
  int lane = threadIdx.x & 63;
  *(f16x8*)&lds[lane * 8] = *(const f16x8*)g;
#endif
}

// ---------------------------- convert kernels ------------------------------

__global__ void conv_logits(const float* __restrict__ src, f16* __restrict__ dst) {
  int idx = blockIdx.x * 256 + threadIdx.x;      // < 65536*128
  int row = idx >> 7, k = idx & 127;
  dst[idx] = (f16)((k < 120) ? src[(size_t)row * 120 + k] : 0.f);
}

__global__ void conv_wt0(const float* __restrict__ w, f16* __restrict__ dst) {
  int idx = blockIdx.x * 256 + threadIdx.x;      // < 2560*128
  int n = idx >> 7, k = idx & 127;
  dst[idx] = (f16)((k < 120) ? w[(size_t)n * 120 + k] : 0.f);
}

__global__ void conv_copy(const float* __restrict__ src, f16* __restrict__ dst, int count) {
  int idx = blockIdx.x * 256 + threadIdx.x;
  if (idx < count) dst[idx] = (f16)src[idx];
}

__global__ void conv_wtl(const float* __restrict__ w, f16* __restrict__ dst) {
  int idx = blockIdx.x * 256 + threadIdx.x;      // < 128*640
  int n = idx / 640, k = idx % 640;
  dst[idx] = (f16)((n < 72) ? w[(size_t)n * 640 + k] : 0.f);
}

// Whh -> pair-packed scan layout (same as R6/R7).
__global__ void conv_whh(const float* __restrict__ whh0, const float* __restrict__ whh,
                         uint32_t* __restrict__ dst) {
  int o = blockIdx.x * 256 + threadIdx.x;        // < 6*2*200*512 = 1228800
  int tid = o & 511;
  int g  = o >> 9;
  int j  = g % 40;
  int g2 = g / 40;
  int i  = g2 % 5;
  int g3 = g2 / 5;                               // 0..11
  int hf = g3 & 1, slot = g3 >> 1;               // slot = layer*2+dir
  int tau = i * 512 + tid;
  int lr = tau >> 2, kq = tau & 3;
  int gate = lr / 160, u = lr - gate * 160;
  int r = gate * 320 + hf * 160 + u;
  int k = kq * 80 + j * 2;
  const float* srcm = (slot < 2) ? (whh0 + ((size_t)slot * 1280 + r) * 320)
                                 : (whh  + ((size_t)(slot - 2) * 1280 + r) * 320);
  f16 lo = (f16)srcm[k], hi = (f16)srcm[k + 1];
  dst[o] = (uint32_t)__builtin_bit_cast(unsigned short, lo) |
           ((uint32_t)__builtin_bit_cast(unsigned short, hi) << 16);
}

// --------------------- gather-GEMM for one time chunk ----------------------
__global__ __launch_bounds__(256)
void gemm_chunk(const f16* __restrict__ A, const f16* __restrict__ W,
                f16* __restrict__ gxc, const int* __restrict__ lens,
                int lda, int kTiles, int c0) {
  __shared__ __align__(16) f16 As[128 * 32];
  __shared__ __align__(16) f16 Ws[2][128 * 32];
  const int tid = threadIdx.x;
  const int lane = tid & 63, wid = tid >> 6;
  const int wm = wid >> 1, wn = wid & 1;
  const int dir = blockIdx.y >> 6, b = blockIdx.y & 63;
  const int n0 = blockIdx.x * 256;
  const int r_base = lane >> 2;                              // 0..15
  const int chs = ((((lane & 3) + (r_base >> 1)) & 3)) * 8;  // swizzled SRC k-chunk
  const int len = lens[b];

  f32x4 acc[4][8] = {};

  for (int kt = 0; kt < kTiles; ++kt) {
    const int k0 = kt * 32;
    __syncthreads();
#pragma unroll
    for (int hh = 0; hh < 2; ++hh) {
      const int c = wid * 2 + hh;
      const int j = c * 16 + r_base;                     // step within chunk
      const int s = c0 * CT + j;
      const int tt = dir ? ((s < len) ? (len - 1 - s) : s) : s;
      stage16(&As[c * 512], A + (size_t)(b * 1024 + tt) * lda + k0 + chs);
    }
#pragma unroll
    for (int hh = 0; hh < 4; ++hh) {
      const int c = wid * 4 + hh;                        // 0..15
      const int tile = c >> 3, cc = c & 7;
      stage16(&Ws[tile][cc * 512],
              W + (size_t)(dir * 1280 + n0 + tile * 128 + cc * 16 + r_base) * lda + k0 + chs);
    }
    __syncthreads();

    const int q = lane >> 4;                 // MFMA k-chunk
    const int l15 = lane & 15;
    const int cs = (q - (l15 >> 1)) & 3;     // swizzled slot holding chunk q
    const int rofs = l15 * 32 + cs * 8;      // f16 units within a 16-row chunk
    f16x8 av[4], wv0[4], wv1[4];
#pragma unroll
    for (int i = 0; i < 4; ++i)
      av[i] = *(const f16x8*)&As[(wm * 4 + i) * 512 + rofs];
#pragma unroll
    for (int i = 0; i < 4; ++i) {
      wv0[i] = *(const f16x8*)&Ws[0][(wn * 4 + i) * 512 + rofs];
      wv1[i] = *(const f16x8*)&Ws[1][(wn * 4 + i) * 512 + rofs];
    }
#pragma unroll
    for (int i = 0; i < 4; ++i)
#pragma unroll
      for (int j = 0; j < 4; ++j) {
        acc[i][j]     = __builtin_amdgcn_mfma_f32_16x16x32_f16(av[i], wv0[j], acc[i][j], 0, 0, 0);
        acc[i][4 + j] = __builtin_amdgcn_mfma_f32_16x16x32_f16(av[i], wv1[j], acc[i][4 + j], 0, 0, 0);
      }
  }

  const int r0 = (lane >> 4) * 4, cn = lane & 15;
  const size_t obase = (size_t)(dir * 64 + b) * CT;
#pragma unroll
  for (int i = 0; i < 4; ++i) {
    const int m = wm * 64 + i * 16 + r0;
#pragma unroll
    for (int j = 0; j < 4; ++j) {
      const int n = n0 + wn * 64 + j * 16 + cn;
#pragma unroll
      for (int r = 0; r < 4; ++r) {
        gxc[(obase + m + r) * 1280 + n]       = (f16)acc[i][j][r];
        gxc[(obase + m + r) * 1280 + n + 128] = (f16)acc[i][4 + j][r];
      }
    }
  }
}

// ------------------------- LSTM scan (one chunk) ---------------------------
// R8 structure: 256 WGs, one (b,dir,half) stream each; agent-scope exchange.
// R15: in-loop barriers are LDS-only (no vmcnt drain).
__global__ void __launch_bounds__(512)
__attribute__((amdgpu_waves_per_eu(2, 2)))
lstm_scan_chunk(const volatile uint32_t* wbuf,      // NOT restrict: may alias
                const f16* __restrict__ gxc,        // [2*64*CT][1280]
                const float* __restrict__ bias,     // [2][1280] this layer
                const int* __restrict__ lens,
                f16* xnext,                         // [65536][640] (no restrict)
                uint32_t* xq,                       // [512][160] tagged words
                f16* hsave,                         // [128][320]
                float* csave,                       // [256][160]
                int layer, int c0) {
  const int wg = blockIdx.x;
  const int half = wg >> 7;
  const int bd = wg & 127;
  const int b = bd >> 1, dir = bd & 1;
  const int tid = threadIdx.x;

  __shared__ __align__(16) f16 hbuf[320];
  __shared__ float ylds[640];
  __shared__ __align__(16) f16 hstage[64 * 160];   // 20 KB ring

  h2v w[5][40];
  {
    const volatile uint32_t* wb =
        wbuf + (size_t)((layer * 2 + dir) * 2 + half) * 200 * 512;
#pragma unroll
    for (int i = 0; i < 5; ++i)
#pragma unroll
      for (int j = 0; j < 40; ++j) {
        uint32_t v = wb[(i * 40 + j) * 512 + tid];
        w[i][j] = __builtin_bit_cast(h2v, v);
      }
  }
  if (tid < 320) hbuf[tid] = (c0 == 0) ? (f16)0.f : hsave[bd * 320 + tid];

  const int len = lens[b];
  const int kq = tid & 3;
  const int qi = tid >> 2;
  const int gu = half * 160 + tid;               // valid when tid<160
  float c_state = 0.f;
  float bi = 0.f, bff = 0.f, bg = 0.f, bo = 0.f;
  if (tid < 160) {
    if (c0 > 0) c_state = csave[wg * 160 + tid];
    const float* bp = bias + dir * 1280 + gu;
    bi = bp[0]; bff = bp[320]; bg = bp[640]; bo = bp[960];
  }
  __syncthreads();   // initial: full barrier (drains hsave/csave loads)

  const size_t grow0 = (size_t)(dir * 64 + b) * CT;

  float gxi = 0.f, gxf = 0.f, gxg = 0.f, gxo = 0.f;
  if (tid < 160) {
    const f16* gp = gxc + grow0 * 1280 + gu;
    gxi = (float)gp[0]; gxf = (float)gp[320]; gxg = (float)gp[640]; gxo = (float)gp[960];
  }

  for (int tl = 0; tl < CT; ++tl) {
    const int s = c0 * CT + tl;
    const uint32_t tag = (uint32_t)(layer * 1024 + s + 1);

    float nxi = 0.f, nxf = 0.f, nxg = 0.f, nxo = 0.f;
    if (tid < 160 && tl + 1 < CT) {
      const f16* gp = gxc + (grow0 + tl + 1) * 1280 + gu;
      nxi = (float)gp[0]; nxf = (float)gp[320]; nxg = (float)gp[640]; nxo = (float)gp[960];
    }

    // ---- y = Whh_half . h  (all threads, b128 LDS reads; broadcast-free) ----
    float a0 = 0.f, a1 = 0.f, a2 = 0.f, a3 = 0.f, a4 = 0.f;
    {
      const u32x4* h4 = (const u32x4*)hbuf;
#pragma unroll
      for (int jb = 0; jb < 5; ++jb) {
        u32x4 p = h4[kq * 10 + jb * 2];
        u32x4 q = h4[kq * 10 + jb * 2 + 1];
        h2v hr[8];
#pragma unroll
        for (int j = 0; j < 4; ++j) hr[j] = __builtin_bit_cast(h2v, p[j]);
#pragma unroll
        for (int j = 0; j < 4; ++j) hr[4 + j] = __builtin_bit_cast(h2v, q[j]);
#pragma unroll
        for (int j = 0; j < 8; ++j) {
          a0 = dot2f(w[0][jb * 8 + j], hr[j], a0);
          a1 = dot2f(w[1][jb * 8 + j], hr[j], a1);
          a2 = dot2f(w[2][jb * 8 + j], hr[j], a2);
          a3 = dot2f(w[3][jb * 8 + j], hr[j], a3);
          a4 = dot2f(w[4][jb * 8 + j], hr[j], a4);
        }
      }
    }
    {
      float av[5] = {a0, a1, a2, a3, a4};
#pragma unroll
      for (int i = 0; i < 5; ++i) {
        float v = av[i];
        v += __shfl_xor(v, 1, 64);
        v += __shfl_xor(v, 2, 64);
        if (kq == 0) ylds[i * 128 + qi] = v;
      }
    }

    if ((tl & 31) == 0 && tl > 0) {
      const int tw = tl - 32;
#pragma unroll
      for (int it = 0; it < 2; ++it) {
        const int slot = it * 512 + tid;
        if (slot < 640) {
          const int r = (int)(((unsigned)slot * 52429u) >> 20);  // slot/20
          const int j = slot - r * 20;
          const int sp = c0 * CT + tw + r;
          const int ttp = dir ? ((sp < len) ? (len - 1 - sp) : sp) : sp;
          f16x8 v = *(const f16x8*)&hstage[((tw + r) & 63) * 160 + j * 8];
          *(f16x8*)&xnext[(size_t)(b * 1024 + ttp) * 640 + dir * 320 + half * 160 + j * 8] = v;
        }
      }
    }
    bar_lds();                                    // B1: ylds ready (LDS only)

    if (tid < 160) {
      const int u = tid;
      float pi = ylds[u]       + gxi + bi;
      float pf = ylds[160 + u] + gxf + bff;
      float pg = ylds[320 + u] + gxg + bg;
      float po = ylds[480 + u] + gxo + bo;
      float ig = fsigm(pi);
      float fg = fsigm(pf);
      float gg = ftanh(pg);
      float og = fsigm(po);
      c_state = fg * c_state + ig * gg;
      float hv = og * ftanh(c_state);
      const f16 hh = (f16)hv;
      const uint32_t word = (tag << 16) |
                            (uint32_t)__builtin_bit_cast(unsigned short, hh);
      __hip_atomic_store(&xq[((bd * 2 + half) * 2 + (s & 1)) * 160 + u], word,
                         __ATOMIC_RELAXED, __HIP_MEMORY_SCOPE_AGENT);
      hbuf[gu] = hh;
      hstage[(tl & 63) * 160 + u] = hh;
    } else if (tid >= 256 && tid < 416) {
      const int u = tid - 256;
      uint32_t pw;
      int spins = 0;
      do {
        pw = __hip_atomic_load(&xq[((bd * 2 + (1 - half)) * 2 + (s & 1)) * 160 + u],
                               __ATOMIC_RELAXED, __HIP_MEMORY_SCOPE_AGENT);
      } while ((pw >> 16) != tag && ++spins < 200000);
      hbuf[(1 - half) * 160 + u] =
          __builtin_bit_cast(f16, (unsigned short)(pw & 0xffffu));
    }
    bar_lds();                                    // B2: hbuf ready (LDS only)

    gxi = nxi; gxf = nxf; gxg = nxg; gxo = nxo;
  }

  {
    const int tw = CT - 32;
#pragma unroll
    for (int it = 0; it < 2; ++it) {
      const int slot = it * 512 + tid;
      if (slot < 640) {
        const int r = (int)(((unsigned)slot * 52429u) >> 20);
        const int j = slot - r * 20;
        const int sp = c0 * CT + tw + r;
        const int ttp = dir ? ((sp < len) ? (len - 1 - sp) : sp) : sp;
        f16x8 v = *(const f16x8*)&hstage[((tw + r) & 63) * 160 + j * 8];
        *(f16x8*)&xnext[(size_t)(b * 1024 + ttp) * 640 + dir * 320 + half * 160 + j * 8] = v;
      }
    }
  }
  if (tid < 160) {
    hsave[bd * 320 + gu] = hbuf[gu];
    csave[wg * 160 + tid] = c_state;
  }
}

// ---------------------- projection GEMM (f32 out) --------------------------
__global__ __launch_bounds__(256)
void gemm_proj(const f16* __restrict__ A, const f16* __restrict__ W,
               float* __restrict__ outf, int lda, int kTiles, int ldo) {
  __shared__ __align__(16) f16 As[128 * 32];
  __shared__ __align__(16) f16 Ws[128 * 32];
  const int tid = threadIdx.x;
  const int lane = tid & 63, wid = tid >> 6;
  const int wm = wid >> 1, wn = wid & 1;
  const int m0 = blockIdx.y * 128, n0 = blockIdx.x * 128;
  const int r_base = lane >> 2;
  const int chs = ((((lane & 3) + (r_base >> 1)) & 3)) * 8;  // swizzled SRC chunk

  f32x4 acc[4][4] = {};

  for (int kt = 0; kt < kTiles; ++kt) {
    const int k0 = kt * 32;
    __syncthreads();
#pragma unroll
    for (int hh = 0; hh < 2; ++hh) {
      const int c = wid * 2 + hh;
      stage16(&As[c * 512], A + (size_t)(m0 + c * 16 + r_base) * lda + k0 + chs);
      stage16(&Ws[c * 512], W + (size_t)(n0 + c * 16 + r_base) * lda + k0 + chs);
    }
    __syncthreads();

    const int q = lane >> 4;
    const int l15 = lane & 15;
    const int cs = (q - (l15 >> 1)) & 3;
    const int rofs = l15 * 32 + cs * 8;
    f16x8 av[4], wv[4];
#pragma unroll
    for (int i = 0; i < 4; ++i)
      av[i] = *(const f16x8*)&As[(wm * 4 + i) * 512 + rofs];
#pragma unroll
    for (int i = 0; i < 4; ++i)
      wv[i] = *(const f16x8*)&Ws[(wn * 4 + i) * 512 + rofs];
#pragma unroll
    for (int i = 0; i < 4; ++i)
#pragma unroll
      for (int j = 0; j < 4; ++j)
        acc[i][j] = __builtin_amdgcn_mfma_f32_16x16x32_f16(av[i], wv[j], acc[i][j], 0, 0, 0);
  }

  const int r0 = (lane >> 4) * 4, cn = lane & 15;
#pragma unroll
  for (int i = 0; i < 4; ++i) {
    const int m = m0 + wm * 64 + i * 16 + r0;
#pragma unroll
    for (int j = 0; j < 4; ++j) {
      const int n = n0 + wn * 64 + j * 16 + cn;
#pragma unroll
      for (int r = 0; r < 4; ++r)
        outf[(size_t)(m + r) * ldo + n] = acc[i][j][r];
    }
  }
}

// ------------------------- logsumexp over K=72 ------------------------------
__global__ void lse_kernel(const float* __restrict__ Z, const float* __restrict__ b_lin,
                           float* __restrict__ lseout) {
  int row = blockIdx.x * 4 + (threadIdx.x >> 6);
  int l = threadIdx.x & 63;
  const float* z = Z + (size_t)row * 128;
  float v0 = (l < 72) ? z[l] + b_lin[l] : NEGF;
  float v1 = (l < 8) ? z[l + 64] + b_lin[l + 64] : NEGF;
  float m = fmaxf(v0, v1);
#pragma unroll
  for (int o = 32; o; o >>= 1) m = fmaxf(m, __shfl_xor(m, o, 64));
  float s = ((l < 72) ? __expf(v0 - m) : 0.f) + ((l < 8) ? __expf(v1 - m) : 0.f);
#pragma unroll
  for (int o = 32; o; o >>= 1) s += __shfl_xor(s, o, 64);
  if (l == 0) lseout[row] = m + __logf(s);
}

// --------------- emission pre-gather: emc[b][t][s] (f16) -------------------
// emc = (Z[t][ext[s]] + b_lin[ext[s]] - lse[t]) * log2(e).  Base-2 domain so
// the ctc recursion uses raw v_exp_f32 / v_log_f32.
__global__ void emz_kernel(const float* __restrict__ Z, const float* __restrict__ lse,
                           const float* __restrict__ b_lin,
                           const int* __restrict__ labels,
                           f16* __restrict__ emc) {
  const int b = blockIdx.y;
  const int t0 = blockIdx.x * 4;
  const int tid = threadIdx.x;   // 256
  __shared__ int ext[200];
  __shared__ float bls[200];
  if (tid < 200) {
    int e = (tid < 193 && (tid & 1)) ? labels[b * 96 + (tid >> 1)] : 0;
    ext[tid] = e;
    bls[tid] = b_lin[e];
  }
  __syncthreads();
#pragma unroll
  for (int dt = 0; dt < 4; ++dt) {
    const int t = t0 + dt;
    const float lst = lse[b * 1024 + t];
    const float* zr = Z + ((size_t)(b * 1024 + t)) * 128;
    for (int s = tid; s < 200; s += 256)
      emc[((size_t)(b * 1024 + t)) * 200 + s] =
          (f16)((zr[ext[s]] + bls[s] - lst) * 1.4426950408889634f);
  }
}

// ------------------------------ CTC forward ---------------------------------
__global__ void ctc_kernel(const f16* __restrict__ emc,
                           const int* __restrict__ labels, const int* __restrict__ inlen,
                           const int* __restrict__ lablen, float* __restrict__ num) {
  const int b = blockIdx.x;
  const int lane = threadIdx.x;          // 64
  __shared__ int ext[200];
  __shared__ float afin[200];

  for (int s = lane; s < 200; s += 64)
    ext[s] = (s < 193 && (s & 1)) ? labels[b * 96 + (s >> 1)] : 0;
  __syncthreads();

  const int L = lablen[b], len = inlen[b];
  const int Send = 2 * L + 1;
  const f16* eb = emc + (size_t)b * 1024 * 200;

  float a[4];
  bool  skp[4], val[4];
#pragma unroll
  for (int j = 0; j < 4; ++j) {
    const int s = lane * 4 + j;
    val[j] = (s < Send) && (s < 193);
    skp[j] = (s < 193) && (s & 1) && (s >= 2) && (ext[s] != ext[s - 2]);
  }
  {
    f16x4v e0 = *(const f16x4v*)&eb[lane * 4];   // t = 0
#pragma unroll
    for (int j = 0; j < 4; ++j) {
      const int s = lane * 4 + j;
      a[j] = (s <= 1 && val[j]) ? (float)e0[j] : NEGF;
    }
  }

  auto step = [&](f16x4v ev) {
    float p3 = __shfl_up(a[3], 1, 64);
    float p2 = __shfl_up(a[2], 1, 64);
    if (lane == 0) { p3 = NEGF; p2 = NEGF; }
    const float x2[4] = {p3, a[0], a[1], a[2]};
    const float x3[4] = {p2, p3, a[0], a[1]};
#pragma unroll
    for (int j = 0; j < 4; ++j) {
      const float xa = a[j], xb = x2[j];
      const float xc = skp[j] ? x3[j] : NEGF;
      const float m = fmaxf(xa, fmaxf(xb, xc));
      const float sum = fexp2(xa - m) + fexp2(xb - m) + fexp2(xc - m);
      const float nv = m + flog2(sum) + (float)ev[j];
      a[j] = val[j] ? nv : NEGF;
    }
  };

  // depth-8 register ring, fully static slot indexing
  f16x4v ring[8];
#pragma unroll
  for (int d = 1; d <= 8; ++d) {
    const int r = (d < len) ? d : (len - 1);
    ring[d & 7] = *(const f16x4v*)&eb[(size_t)r * 200 + lane * 4];
  }

  int t = 1;
  for (; t + 8 <= len; t += 8) {
#pragma unroll
    for (int k = 0; k < 8; ++k) {
      const int slot = (1 + k) & 7;        // t == 1 (mod 8)
      f16x4v ev = ring[slot];
      const int tp = t + k + 8;
      if (tp < len)
        ring[slot] = *(const f16x4v*)&eb[(size_t)tp * 200 + lane * 4];
      step(ev);
    }
  }
  for (; t < len; ++t)
    step(*(const f16x4v*)&eb[(size_t)t * 200 + lane * 4]);

#pragma unroll
  for (int j = 0; j < 4; ++j) {
    const int s = lane * 4 + j;
    if (s < 193) afin[s] = a[j];
  }
  __syncthreads();
  if (lane == 0) {
    const float aL = afin[2 * L], aLm1 = afin[2 * L - 1];
    const float m = fmaxf(aL, aLm1);
    // back to natural log for the final reduction
    num[b] = 0.6931471805599453f * (m + flog2(fexp2(aL - m) + fexp2(aLm1 - m)));
  }
}

__global__ void final_kernel(const float* __restrict__ num, float* __restrict__ out) {
  int l = threadIdx.x;  // 64
  float v = -1.1f * num[l];
#pragma unroll
  for (int o = 32; o; o >>= 1) v += __shfl_xor(v, o, 64);
  if (l == 0) out[0] = v * (1.f / 64.f);
}

__global__ void sentinel_kernel(float* __restrict__ out, float code) { out[0] = code; }

// ------------------------------ launcher ------------------------------------
extern "C" void kernel_launch(void* const* d_in, const int* in_sizes, int n_in,
                              void* d_out, int out_size, void* d_ws, size_t ws_size,
                              hipStream_t stream) {
  (void)in_sizes; (void)n_in; (void)out_size;

  const float* logits   = (const float*)d_in[0];
  const int*   labels   = (const int*)d_in[1];
  const int*   in_lens  = (const int*)d_in[2];
  const int*   lab_lens = (const int*)d_in[3];
  const float* Wih0     = (const float*)d_in[4];
  const float* Whh0     = (const float*)d_in[5];
  const float* b0       = (const float*)d_in[6];
  const float* Wih      = (const float*)d_in[7];
  const float* Whh      = (const float*)d_in[8];
  const float* bb       = (const float*)d_in[9];
  const float* W_lin    = (const float*)d_in[10];
  const float* b_lin    = (const float*)d_in[11];

  const size_t NEED = (size_t)224 * 1024 * 1024;
  if (ws_size < NEED) {
    sentinel_kernel<<<1, 1, 0, stream>>>((float*)d_out, -(float)(ws_size >> 20));
    return;
  }

  char* ws = (char*)d_ws;
  size_t off = 0;
  auto alloc = [&](size_t bytes) -> char* {
    char* p = ws + off;
    off += (bytes + 255) & ~(size_t)255;
    return p;
  };
  f16*      Xa     = (f16*)alloc((size_t)65536 * 640 * 2);        // 83.9 MB
  f16*      Xb     = (f16*)alloc((size_t)65536 * 640 * 2);        // 83.9 MB
  f16*      gxc    = (f16*)alloc((size_t)2 * 64 * CT * 1280 * 2); // 41.9 MB
  f16*      Wt0    = (f16*)alloc((size_t)2560 * 128 * 2);
  f16*      Wt12   = (f16*)alloc((size_t)2 * 2560 * 640 * 2);
  f16*      WtL    = (f16*)alloc((size_t)128 * 640 * 2);
  uint32_t* whh16  = (uint32_t*)alloc((size_t)6 * 2 * 200 * 512 * 4);
  float*    lseb   = (float*)alloc((size_t)65536 * 4);
  float*    num    = (float*)alloc(64 * 4);
  uint32_t* xq     = (uint32_t*)alloc((size_t)512 * 160 * 4);
  f16*      hsave  = (f16*)alloc((size_t)128 * 320 * 2);
  float*    csave  = (float*)alloc((size_t)256 * 160 * 4);
  // aliases (disjoint lifetimes)
  f16*      A0     = Xb;           // dead after layer 0; Xb first written layer 1
  float*    Z      = (float*)gxc;  // gxc dead after layer-2 scan
  f16*      emc    = Xa;           // Xa dead after gemm_proj

  hipMemsetAsync(xq, 0, (size_t)512 * 160 * 4, stream);

  conv_logits<<<32768, 256, 0, stream>>>(logits, A0);
  conv_wt0<<<1280, 256, 0, stream>>>(Wih0, Wt0);
  conv_copy<<<12800, 256, 0, stream>>>(Wih, Wt12, 3276800);
  conv_wtl<<<320, 256, 0, stream>>>(W_lin, WtL);
  conv_whh<<<4800, 256, 0, stream>>>(Whh0, Whh, whh16);

  // layer 0: A0 -> Xa
  for (int c = 0; c < 1024 / CT; ++c) {
    gemm_chunk<<<dim3(5, 128), 256, 0, stream>>>(A0, Wt0, gxc, in_lens, 128, 4, c);
    lstm_scan_chunk<<<256, 512, 0, stream>>>(whh16, gxc, b0, in_lens, Xa, xq,
                                             hsave, csave, 0, c);
  }
  // layer 1: Xa -> Xb
  for (int c = 0; c < 1024 / CT; ++c) {
    gemm_chunk<<<dim3(5, 128), 256, 0, stream>>>(Xa, Wt12, gxc, in_lens, 640, 20, c);
    lstm_scan_chunk<<<256, 512, 0, stream>>>(whh16, gxc, bb, in_lens, Xb, xq,
                                             hsave, csave, 1, c);
  }
  // layer 2: Xb -> Xa
  for (int c = 0; c < 1024 / CT; ++c) {
    gemm_chunk<<<dim3(5, 128), 256, 0, stream>>>(Xb, Wt12 + (size_t)2560 * 640, gxc,
                                                 in_lens, 640, 20, c);
    lstm_scan_chunk<<<256, 512, 0, stream>>>(whh16, gxc, bb + 2560, in_lens, Xa, xq,
                                             hsave, csave, 2, c);
  }
  // projection: Xa -> Z (f32)
  gemm_proj<<<dim3(1, 512), 256, 0, stream>>>(Xa, WtL, Z, 640, 20, 128);

  lse_kernel<<<16384, 256, 0, stream>>>(Z, b_lin, lseb);
  emz_kernel<<<dim3(256, 64), 256, 0, stream>>>(Z, lseb, b_lin, labels, emc);
  ctc_kernel<<<64, 64, 0, stream>>>(emc, labels, in_lens, lab_lens, num);
  final_kernel<<<1, 64, 0, stream>>>(num, (float*)d_out);
}